// Round 4
// baseline (830.207 us; speedup 1.0000x reference)
//
#include <hip/hip_runtime.h>

#define NN 100000
#define NE 3200000
#define NBUCK 782   // ceil(NN/128)
#define EPB 8192
#define NCB 391     // ceil(NE/EPB)
#define CSHIFT 12   // column chunk = 4096 source rows (2MB of 256-dim bf16 H)
#define NCH 25      // ceil(100000/4096)
#define NBIN (128 * NCH)  // 3200 (row,chunk) bins per bucket
#define BPT 13      // bins per thread in k_bsort scan: 13*256 = 3328 >= 3200

typedef __attribute__((ext_vector_type(8))) short bf16x8;
typedef __attribute__((ext_vector_type(4))) float f32x4;

__device__ __forceinline__ ushort f2bf(float f) {
  unsigned u = __builtin_bit_cast(unsigned, f);
  u = (u + 0x7FFFu + ((u >> 16) & 1u)) >> 16;
  return (ushort)u;
}
__device__ __forceinline__ float bf2f(ushort h) {
  return __builtin_bit_cast(float, ((unsigned)h) << 16);
}
__device__ __forceinline__ void gl2lds16(const void* g, void* s) {
  __builtin_amdgcn_global_load_lds((const __attribute__((address_space(1))) void*)g,
                                   (__attribute__((address_space(3))) void*)s, 16, 0, 0);
}

// ---------------- CSR build: two-pass block-local counting sort ----------------
__global__ __launch_bounds__(256) void k_cnt(const int* __restrict__ row, int* __restrict__ ghist,
                                             int* __restrict__ bcnt) {
  __shared__ int h[NBUCK];
  int blk = blockIdx.x, tid = threadIdx.x;
  for (int i = tid; i < NBUCK; i += 256) h[i] = 0;
  __syncthreads();
  int lo = blk * EPB, hi = lo + EPB; if (hi > NE) hi = NE;
  for (int i = lo + tid * 4; i < hi; i += 1024) {
    int4 r = *(const int4*)(row + i);
    atomicAdd(&h[r.x >> 7], 1);
    atomicAdd(&h[r.y >> 7], 1);
    atomicAdd(&h[r.z >> 7], 1);
    atomicAdd(&h[r.w >> 7], 1);
  }
  __syncthreads();
  for (int i = tid; i < NBUCK; i += 256) {
    ghist[(size_t)i * NCB + blk] = h[i];
    if (h[i]) atomicAdd(&bcnt[i], h[i]);
  }
}

__global__ __launch_bounds__(1024) void k_bscan(const int* __restrict__ bcnt, int* __restrict__ bbase) {
  __shared__ int s[1024];
  int t = threadIdx.x;
  s[t] = (t < NBUCK) ? bcnt[t] : 0;
  __syncthreads();
  for (int o = 1; o < 1024; o <<= 1) {
    int v = (t >= o) ? s[t - o] : 0;
    __syncthreads();
    s[t] += v;
    __syncthreads();
  }
  if (t < NBUCK) bbase[t] = t ? s[t - 1] : 0;
}

__global__ __launch_bounds__(64) void k_scan3(int* __restrict__ ghist, const int* __restrict__ bbase) {
  int b = blockIdx.x, lane = threadIdx.x;
  int carry = bbase[b];
#pragma unroll
  for (int r = 0; r < 7; ++r) {
    int idx = r * 64 + lane;
    int v = (idx < NCB) ? ghist[(size_t)b * NCB + idx] : 0;
    int s = v;
#pragma unroll
    for (int o = 1; o < 64; o <<= 1) { int t = __shfl_up(s, o, 64); if (lane >= o) s += t; }
    if (idx < NCB) ghist[(size_t)b * NCB + idx] = carry + s - v;
    carry += __shfl(s, 63, 64);
  }
}

__global__ __launch_bounds__(256) void k_place(const int* __restrict__ row, const int* __restrict__ col,
                                               const float* __restrict__ w, const int* __restrict__ ghist,
                                               int2* __restrict__ bdata) {
  __shared__ int offs[NBUCK];
  int blk = blockIdx.x, tid = threadIdx.x;
  for (int i = tid; i < NBUCK; i += 256) offs[i] = ghist[(size_t)i * NCB + blk];
  __syncthreads();
  int lo = blk * EPB, hi = lo + EPB; if (hi > NE) hi = NE;
  for (int i = lo + tid * 4; i < hi; i += 1024) {
    int4 r = *(const int4*)(row + i);
    int4 c = *(const int4*)(col + i);
    float4 ww = *(const float4*)(w + i);
    int p;
    p = atomicAdd(&offs[r.x >> 7], 1); bdata[p] = make_int2(((r.x & 127) << 17) | c.x, __float_as_int(ww.x));
    p = atomicAdd(&offs[r.y >> 7], 1); bdata[p] = make_int2(((r.y & 127) << 17) | c.y, __float_as_int(ww.y));
    p = atomicAdd(&offs[r.z >> 7], 1); bdata[p] = make_int2(((r.z & 127) << 17) | c.z, __float_as_int(ww.z));
    p = atomicAdd(&offs[r.w >> 7], 1); bdata[p] = make_int2(((r.w & 127) << 17) | c.w, __float_as_int(ww.w));
  }
}

// Pass 3: one block per bucket; sort by (row, col-chunk) -> rp + chunk-ordered cw.
// Chunk ordering makes resident spmm waves gather from the same 2MB slice of H
// at roughly the same time -> L2-resident gathers.
__global__ __launch_bounds__(256) void k_bsort(const int* __restrict__ bcnt, const int* __restrict__ bbase,
                                               const int2* __restrict__ bdata, int2* __restrict__ cw,
                                               int* __restrict__ rp) {
  __shared__ int sc[NBIN];
  __shared__ int tt[256];
  int b = blockIdx.x, t = threadIdx.x;
  int n = bcnt[b], base = bbase[b];
  for (int i = t; i < NBIN; i += 256) sc[i] = 0;
  __syncthreads();
  for (int i = t; i < n; i += 256) {
    int e = bdata[(size_t)base + i].x;
    int bin = (e >> 17) * NCH + ((e & 0x1FFFF) >> CSHIFT);
    atomicAdd(&sc[bin], 1);
  }
  __syncthreads();
  // two-level exclusive scan over NBIN bins: serial per thread + Hillis-Steele over thread totals
  int lo = t * BPT;
  int lc[BPT];
  int sum = 0;
#pragma unroll
  for (int k = 0; k < BPT; ++k) {
    int idx = lo + k;
    int v = (idx < NBIN) ? sc[idx] : 0;
    lc[k] = sum;
    sum += v;
  }
  tt[t] = sum;
  __syncthreads();
  for (int o = 1; o < 256; o <<= 1) {
    int v = (t >= o) ? tt[t - o] : 0;
    __syncthreads();
    tt[t] += v;
    __syncthreads();
  }
  int texcl = t ? tt[t - 1] : 0;
  __syncthreads();  // all reads of sc done before overwrite
#pragma unroll
  for (int k = 0; k < BPT; ++k) {
    int idx = lo + k;
    if (idx < NBIN) {
      int off = texcl + lc[k];
      sc[idx] = off;                                   // bin -> local exclusive offset
      if ((idx % NCH) == 0) rp[b * 128 + idx / NCH] = base + off;  // row pointer (c==0 bin)
    }
  }
  __syncthreads();
  for (int i = t; i < n; i += 256) {
    int2 e = bdata[(size_t)base + i];
    int bin = (e.x >> 17) * NCH + ((e.x & 0x1FFFF) >> CSHIFT);
    int p = atomicAdd(&sc[bin], 1);
    cw[base + p] = make_int2(e.x & 0x1FFFF, e.y);
  }
}

// ---------------- weight prep: fold BN, transpose to [N][K], cast bf16 ----------------
__global__ __launch_bounds__(256) void k_prep(const float* __restrict__ W, const float* __restrict__ b,
                                              const float* __restrict__ g, const float* __restrict__ be,
                                              const float* __restrict__ m, const float* __restrict__ v,
                                              ushort* __restrict__ Wt, float* __restrict__ bp, int Ncol) {
  int j = blockIdx.x, k = threadIdx.x;
  float val = 0.f;
  if (j < Ncol) {
    float s = 1.f, t = 0.f;
    if (g) { s = g[j] * rsqrtf(v[j] + 1e-5f); t = be[j] - m[j] * s; }
    val = W[(size_t)k * Ncol + j] * s;
    if (k == 0) bp[j] = b[j] * s + t;
  } else if (k == 0) bp[j] = 0.f;
  Wt[(size_t)j * 256 + k] = f2bf(val);
}

// ---------------- x fp32 -> bf16 ----------------
__global__ __launch_bounds__(256) void k_f2bf8(const float* __restrict__ x, ushort* __restrict__ o) {
  size_t i = ((size_t)blockIdx.x * 256 + threadIdx.x) * 8;
  float4 u = *(const float4*)(x + i);
  float4 v = *(const float4*)(x + i + 4);
  ushort4 r0; r0.x = f2bf(u.x); r0.y = f2bf(u.y); r0.z = f2bf(u.z); r0.w = f2bf(u.w);
  ushort4 r1; r1.x = f2bf(v.x); r1.y = f2bf(v.y); r1.z = f2bf(v.z); r1.w = f2bf(v.w);
  *(ushort4*)(o + i) = r0;
  *(ushort4*)(o + i + 4) = r1;
}

// ---------------- bf16 MFMA GEMM: C[M x ncst] = A[M x 256] @ Wt^T, + bias, bf16 out ----------------
__global__ __launch_bounds__(256) void k_gemm(const ushort* __restrict__ A, const ushort* __restrict__ Bt,
                                              const float* __restrict__ bp, ushort* __restrict__ C,
                                              int M, int ldc, int ncst) {
  __shared__ ushort sA[128 * 64];
  __shared__ ushort sB[128 * 64];
  const int tid = threadIdx.x;
  const int lane = tid & 63;
  const int wave = tid >> 6;
  const int wm = wave >> 1, wn = wave & 1;
  const int bm = blockIdx.x, bn = blockIdx.y;

  f32x4 acc[4][4];
#pragma unroll
  for (int a = 0; a < 4; ++a)
#pragma unroll
    for (int b = 0; b < 4; ++b) acc[a][b] = (f32x4){0.f, 0.f, 0.f, 0.f};

  const char* Ab = (const char*)A;
  const char* Bb = (const char*)Bt;
  char* sAb = (char*)sA;
  char* sBb = (char*)sB;

  for (int kt = 0; kt < 4; ++kt) {
#pragma unroll
    for (int it = 0; it < 4; ++it) {
      int o = tid * 16 + it * 4096;
      int r = o >> 7, kb = o & 127;
      int ra = bm * 128 + r; if (ra >= M) ra = M - 1;
      gl2lds16(Ab + (size_t)ra * 512 + kt * 128 + kb, sAb + o);
      gl2lds16(Bb + (size_t)(bn * 128 + r) * 512 + kt * 128 + kb, sBb + o);
    }
    __syncthreads();
#pragma unroll
    for (int kk = 0; kk < 2; ++kk) {
      int kByte = kk * 64 + ((lane >> 4) << 4);
      bf16x8 af[4], bfr[4];
#pragma unroll
      for (int mi = 0; mi < 4; ++mi)
        af[mi] = *(const bf16x8*)(sAb + (wm * 64 + mi * 16 + (lane & 15)) * 128 + kByte);
#pragma unroll
      for (int ni = 0; ni < 4; ++ni)
        bfr[ni] = *(const bf16x8*)(sBb + (wn * 64 + ni * 16 + (lane & 15)) * 128 + kByte);
#pragma unroll
      for (int mi = 0; mi < 4; ++mi)
#pragma unroll
        for (int ni = 0; ni < 4; ++ni)
          acc[mi][ni] = __builtin_amdgcn_mfma_f32_16x16x32_bf16(af[mi], bfr[ni], acc[mi][ni], 0, 0, 0);
    }
    __syncthreads();
  }

  const int r0 = bm * 128 + wm * 64 + ((lane >> 4) << 2);
  const int c0 = bn * 128 + wn * 64 + (lane & 15);
#pragma unroll
  for (int ni = 0; ni < 4; ++ni) {
    int col = c0 + ni * 16;
    if (col >= ncst) continue;
    float bpv = bp[col];
#pragma unroll
    for (int mi = 0; mi < 4; ++mi)
#pragma unroll
      for (int i = 0; i < 4; ++i) {
        int row = r0 + mi * 16 + i;
        if (row < M) C[(size_t)row * ldc + col] = f2bf(acc[mi][ni][i] + bpv);
      }
  }
}

// ---------------- SpMM 256-dim: Y[i,:] = relu(sum w_e * H[col_e,:]), one wave/node ----------------
__global__ __launch_bounds__(256) void k_spmm256(const int* __restrict__ rp, const int2* __restrict__ cw,
                                                 const ushort* __restrict__ H, ushort* __restrict__ Y) {
  int node = blockIdx.x * 4 + (threadIdx.x >> 6);
  int lane = threadIdx.x & 63;
  int s = rp[node], e = rp[node + 1];
  float a0 = 0.f, a1 = 0.f, a2 = 0.f, a3 = 0.f;
  const ushort* Hl = H + (lane << 2);
  int i = s;
  for (; i + 4 <= e; i += 4) {
    int2 p0 = cw[i], p1 = cw[i + 1], p2 = cw[i + 2], p3 = cw[i + 3];
    ushort4 h0 = *(const ushort4*)(Hl + (size_t)p0.x * 256);
    ushort4 h1 = *(const ushort4*)(Hl + (size_t)p1.x * 256);
    ushort4 h2 = *(const ushort4*)(Hl + (size_t)p2.x * 256);
    ushort4 h3 = *(const ushort4*)(Hl + (size_t)p3.x * 256);
    float w0 = __int_as_float(p0.y), w1 = __int_as_float(p1.y);
    float w2 = __int_as_float(p2.y), w3 = __int_as_float(p3.y);
    a0 += w0 * bf2f(h0.x); a1 += w0 * bf2f(h0.y); a2 += w0 * bf2f(h0.z); a3 += w0 * bf2f(h0.w);
    a0 += w1 * bf2f(h1.x); a1 += w1 * bf2f(h1.y); a2 += w1 * bf2f(h1.z); a3 += w1 * bf2f(h1.w);
    a0 += w2 * bf2f(h2.x); a1 += w2 * bf2f(h2.y); a2 += w2 * bf2f(h2.z); a3 += w2 * bf2f(h2.w);
    a0 += w3 * bf2f(h3.x); a1 += w3 * bf2f(h3.y); a2 += w3 * bf2f(h3.z); a3 += w3 * bf2f(h3.w);
  }
  for (; i < e; ++i) {
    int2 p = cw[i];
    ushort4 h = *(const ushort4*)(Hl + (size_t)p.x * 256);
    float w = __int_as_float(p.y);
    a0 += w * bf2f(h.x); a1 += w * bf2f(h.y); a2 += w * bf2f(h.z); a3 += w * bf2f(h.w);
  }
  a0 = fmaxf(a0, 0.f); a1 = fmaxf(a1, 0.f); a2 = fmaxf(a2, 0.f); a3 = fmaxf(a3, 0.f);
  ushort4 o;
  o.x = f2bf(a0); o.y = f2bf(a1); o.z = f2bf(a2); o.w = f2bf(a3);
  *(ushort4*)(Y + (size_t)node * 256 + (lane << 2)) = o;
}

// ---------------- SpMM 64-dim + fused log_softmax, fp32 out ----------------
__global__ __launch_bounds__(256) void k_spmm64(const int* __restrict__ rp, const int2* __restrict__ cw,
                                                const ushort* __restrict__ H, float* __restrict__ out) {
  int node = blockIdx.x * 4 + (threadIdx.x >> 6);
  int lane = threadIdx.x & 63;
  int s = rp[node], e = rp[node + 1];
  float a = 0.f;
  int i = s;
  for (; i + 4 <= e; i += 4) {
    int2 p0 = cw[i], p1 = cw[i + 1], p2 = cw[i + 2], p3 = cw[i + 3];
    float h0 = bf2f(H[(size_t)p0.x * 64 + lane]);
    float h1 = bf2f(H[(size_t)p1.x * 64 + lane]);
    float h2 = bf2f(H[(size_t)p2.x * 64 + lane]);
    float h3 = bf2f(H[(size_t)p3.x * 64 + lane]);
    a += __int_as_float(p0.y) * h0 + __int_as_float(p1.y) * h1
       + __int_as_float(p2.y) * h2 + __int_as_float(p3.y) * h3;
  }
  for (; i < e; ++i) {
    int2 p = cw[i];
    a += __int_as_float(p.y) * bf2f(H[(size_t)p.x * 64 + lane]);
  }
  float mx = a;
#pragma unroll
  for (int o = 32; o > 0; o >>= 1) mx = fmaxf(mx, __shfl_xor(mx, o, 64));
  float ex = expf(a - mx);
  float sum = ex;
#pragma unroll
  for (int o = 32; o > 0; o >>= 1) sum += __shfl_xor(sum, o, 64);
  out[(size_t)node * 64 + lane] = (a - mx) - logf(sum);
}

extern "C" void kernel_launch(void* const* d_in, const int* in_sizes, int n_in,
                              void* d_out, int out_size, void* d_ws, size_t ws_size,
                              hipStream_t stream) {
  const float* x   = (const float*)d_in[0];
  const int* erow  = (const int*)d_in[1];
  const int* ecol  = (const int*)d_in[2];
  const float* ew  = (const float*)d_in[3];
  const float* W1  = (const float*)d_in[4];
  const float* b1  = (const float*)d_in[5];
  const float* g1  = (const float*)d_in[6];
  const float* be1 = (const float*)d_in[7];
  const float* m1  = (const float*)d_in[8];
  const float* v1  = (const float*)d_in[9];
  const float* W2  = (const float*)d_in[10];
  const float* b2  = (const float*)d_in[11];
  const float* g2  = (const float*)d_in[12];
  const float* be2 = (const float*)d_in[13];
  const float* m2  = (const float*)d_in[14];
  const float* v2  = (const float*)d_in[15];
  const float* W3  = (const float*)d_in[16];
  const float* b3  = (const float*)d_in[17];

  char* ws = (char*)d_ws;
  size_t off = 0;
  auto carve = [&](size_t bytes) -> void* {
    void* p = ws + off;
    off += (bytes + 511) & ~(size_t)511;
    return p;
  };
  int* bcnt   = (int*)carve((size_t)NBUCK * 4);
  int* bbase  = (int*)carve((size_t)NBUCK * 4);
  int* ghist  = (int*)carve((size_t)NBUCK * NCB * 4);
  int* rp     = (int*)carve((size_t)(NBUCK * 128 + 1) * 4);
  int2* cw    = (int2*)carve((size_t)NE * 8);
  ushort* W1t = (ushort*)carve(256 * 256 * 2);
  ushort* W2t = (ushort*)carve(256 * 256 * 2);
  ushort* W3t = (ushort*)carve(128 * 256 * 2);
  float* bp1  = (float*)carve(256 * 4);
  float* bp2  = (float*)carve(256 * 4);
  float* bp3  = (float*)carve(128 * 4);
  ushort* bufA = (ushort*)carve((size_t)NN * 256 * 2);
  ushort* bufB = (ushort*)carve((size_t)NN * 256 * 2);
  ushort* bufC = (ushort*)carve((size_t)NN * 64 * 2);
  if (off > ws_size) return;

  // bucket scratch aliases bufA (not live until k_f2bf8): NE*8 = 25.6MB <= 51.2MB
  int2* bdata = (int2*)bufA;

  // CSR build (two-pass block-local counting sort; edges chunk-ordered within row)
  hipMemsetAsync(bcnt, 0, (size_t)NBUCK * 4, stream);
  k_cnt<<<NCB, 256, 0, stream>>>(erow, ghist, bcnt);
  k_bscan<<<1, 1024, 0, stream>>>(bcnt, bbase);
  k_scan3<<<NBUCK, 64, 0, stream>>>(ghist, bbase);
  k_place<<<NCB, 256, 0, stream>>>(erow, ecol, ew, ghist, bdata);
  k_bsort<<<NBUCK, 256, 0, stream>>>(bcnt, bbase, bdata, cw, rp);

  // weights (BN folded, transposed, bf16)
  k_prep<<<256, 256, 0, stream>>>(W1, b1, g1, be1, m1, v1, W1t, bp1, 256);
  k_prep<<<256, 256, 0, stream>>>(W2, b2, g2, be2, m2, v2, W2t, bp2, 256);
  k_prep<<<128, 256, 0, stream>>>(W3, b3, nullptr, nullptr, nullptr, nullptr, W3t, bp3, 64);

  // x -> bf16
  k_f2bf8<<<(NN * 256) / (256 * 8), 256, 0, stream>>>(x, bufA);

  const int gm = (NN + 127) / 128;
  // layer 1
  k_gemm<<<dim3(gm, 2), 256, 0, stream>>>(bufA, W1t, bp1, bufB, NN, 256, 256);
  k_spmm256<<<NN / 4, 256, 0, stream>>>(rp, cw, bufB, bufA);
  // layer 2
  k_gemm<<<dim3(gm, 2), 256, 0, stream>>>(bufA, W2t, bp2, bufB, NN, 256, 256);
  k_spmm256<<<NN / 4, 256, 0, stream>>>(rp, cw, bufB, bufA);
  // output layer
  k_gemm<<<dim3(gm, 1), 256, 0, stream>>>(bufA, W3t, bp3, bufC, NN, 64, 64);
  k_spmm64<<<NN / 4, 256, 0, stream>>>(rp, cw, bufC, (float*)d_out);
}

// Round 5
// 784.107 us; speedup vs baseline: 1.0588x; 1.0588x over previous
//
#include <hip/hip_runtime.h>

#define NN 100000
#define NE 3200000
#define NBUCK 782   // ceil(NN/128)
#define EPB 8192
#define NCB 391     // ceil(NE/EPB)

typedef __attribute__((ext_vector_type(8))) short bf16x8;
typedef __attribute__((ext_vector_type(4))) float f32x4;
typedef __attribute__((ext_vector_type(2))) float f32x2;

__device__ __forceinline__ ushort f2bf(float f) {
  unsigned u = __builtin_bit_cast(unsigned, f);
  u = (u + 0x7FFFu + ((u >> 16) & 1u)) >> 16;
  return (ushort)u;
}
__device__ __forceinline__ float bf2f(ushort h) {
  return __builtin_bit_cast(float, ((unsigned)h) << 16);
}
// decode packed 2x bf16 -> 2x f32 (2 VALU)
__device__ __forceinline__ f32x2 bfpair(unsigned u) {
  f32x2 r;
  r.x = __builtin_bit_cast(float, u << 16);
  r.y = __builtin_bit_cast(float, u & 0xffff0000u);
  return r;
}
__device__ __forceinline__ void gl2lds16(const void* g, void* s) {
  __builtin_amdgcn_global_load_lds((const __attribute__((address_space(1))) void*)g,
                                   (__attribute__((address_space(3))) void*)s, 16, 0, 0);
}

// ---------------- CSR build: two-pass block-local counting sort ----------------
__global__ __launch_bounds__(256) void k_cnt(const int* __restrict__ row, int* __restrict__ ghist,
                                             int* __restrict__ bcnt) {
  __shared__ int h[NBUCK];
  int blk = blockIdx.x, tid = threadIdx.x;
  for (int i = tid; i < NBUCK; i += 256) h[i] = 0;
  __syncthreads();
  int lo = blk * EPB, hi = lo + EPB; if (hi > NE) hi = NE;
  for (int i = lo + tid * 4; i < hi; i += 1024) {
    int4 r = *(const int4*)(row + i);
    atomicAdd(&h[r.x >> 7], 1);
    atomicAdd(&h[r.y >> 7], 1);
    atomicAdd(&h[r.z >> 7], 1);
    atomicAdd(&h[r.w >> 7], 1);
  }
  __syncthreads();
  for (int i = tid; i < NBUCK; i += 256) {
    ghist[(size_t)i * NCB + blk] = h[i];
    if (h[i]) atomicAdd(&bcnt[i], h[i]);
  }
}

__global__ __launch_bounds__(1024) void k_bscan(const int* __restrict__ bcnt, int* __restrict__ bbase) {
  __shared__ int s[1024];
  int t = threadIdx.x;
  s[t] = (t < NBUCK) ? bcnt[t] : 0;
  __syncthreads();
  for (int o = 1; o < 1024; o <<= 1) {
    int v = (t >= o) ? s[t - o] : 0;
    __syncthreads();
    s[t] += v;
    __syncthreads();
  }
  if (t < NBUCK) bbase[t] = t ? s[t - 1] : 0;
}

__global__ __launch_bounds__(64) void k_scan3(int* __restrict__ ghist, const int* __restrict__ bbase) {
  int b = blockIdx.x, lane = threadIdx.x;
  int carry = bbase[b];
#pragma unroll
  for (int r = 0; r < 7; ++r) {
    int idx = r * 64 + lane;
    int v = (idx < NCB) ? ghist[(size_t)b * NCB + idx] : 0;
    int s = v;
#pragma unroll
    for (int o = 1; o < 64; o <<= 1) { int t = __shfl_up(s, o, 64); if (lane >= o) s += t; }
    if (idx < NCB) ghist[(size_t)b * NCB + idx] = carry + s - v;
    carry += __shfl(s, 63, 64);
  }
}

__global__ __launch_bounds__(256) void k_place(const int* __restrict__ row, const int* __restrict__ col,
                                               const float* __restrict__ w, const int* __restrict__ ghist,
                                               int2* __restrict__ bdata) {
  __shared__ int offs[NBUCK];
  int blk = blockIdx.x, tid = threadIdx.x;
  for (int i = tid; i < NBUCK; i += 256) offs[i] = ghist[(size_t)i * NCB + blk];
  __syncthreads();
  int lo = blk * EPB, hi = lo + EPB; if (hi > NE) hi = NE;
  for (int i = lo + tid * 4; i < hi; i += 1024) {
    int4 r = *(const int4*)(row + i);
    int4 c = *(const int4*)(col + i);
    float4 ww = *(const float4*)(w + i);
    int p;
    p = atomicAdd(&offs[r.x >> 7], 1); bdata[p] = make_int2(((r.x & 127) << 17) | c.x, __float_as_int(ww.x));
    p = atomicAdd(&offs[r.y >> 7], 1); bdata[p] = make_int2(((r.y & 127) << 17) | c.y, __float_as_int(ww.y));
    p = atomicAdd(&offs[r.z >> 7], 1); bdata[p] = make_int2(((r.z & 127) << 17) | c.z, __float_as_int(ww.z));
    p = atomicAdd(&offs[r.w >> 7], 1); bdata[p] = make_int2(((r.w & 127) << 17) | c.w, __float_as_int(ww.w));
  }
}

// Pass 3: one block per bucket; LDS 128-row hist + scan -> rp, final row-sorted cw
__global__ __launch_bounds__(256) void k_bsort(const int* __restrict__ bcnt, const int* __restrict__ bbase,
                                               const int2* __restrict__ bdata, int2* __restrict__ cw,
                                               int* __restrict__ rp) {
  __shared__ int sc[128], lpos[128];
  int b = blockIdx.x, t = threadIdx.x;
  int n = bcnt[b], base = bbase[b];
  if (t < 128) sc[t] = 0;
  __syncthreads();
  for (int i = t; i < n; i += 256) {
    int r = bdata[(size_t)base + i].x >> 17;
    atomicAdd(&sc[r], 1);
  }
  __syncthreads();
  for (int o = 1; o < 128; o <<= 1) {
    int v = (t < 128 && t >= o) ? sc[t - o] : 0;
    __syncthreads();
    if (t < 128) sc[t] += v;
    __syncthreads();
  }
  if (t < 128) {
    int excl = t ? sc[t - 1] : 0;
    lpos[t] = excl;
    int grow = b * 128 + t;
    if (grow <= NN) rp[grow] = base + excl;
  }
  __syncthreads();
  for (int i = t; i < n; i += 256) {
    int2 e = bdata[(size_t)base + i];
    int r = e.x >> 17;
    int p = atomicAdd(&lpos[r], 1);
    cw[base + p] = make_int2(e.x & 0x1FFFF, e.y);
  }
}

// ---------------- weight prep: fold BN, transpose to [N][K], cast bf16 ----------------
__global__ __launch_bounds__(256) void k_prep(const float* __restrict__ W, const float* __restrict__ b,
                                              const float* __restrict__ g, const float* __restrict__ be,
                                              const float* __restrict__ m, const float* __restrict__ v,
                                              ushort* __restrict__ Wt, float* __restrict__ bp, int Ncol) {
  int j = blockIdx.x, k = threadIdx.x;
  float val = 0.f;
  if (j < Ncol) {
    float s = 1.f, t = 0.f;
    if (g) { s = g[j] * rsqrtf(v[j] + 1e-5f); t = be[j] - m[j] * s; }
    val = W[(size_t)k * Ncol + j] * s;
    if (k == 0) bp[j] = b[j] * s + t;
  } else if (k == 0) bp[j] = 0.f;
  Wt[(size_t)j * 256 + k] = f2bf(val);
}

// ---------------- x fp32 -> bf16 ----------------
__global__ __launch_bounds__(256) void k_f2bf8(const float* __restrict__ x, ushort* __restrict__ o) {
  size_t i = ((size_t)blockIdx.x * 256 + threadIdx.x) * 8;
  float4 u = *(const float4*)(x + i);
  float4 v = *(const float4*)(x + i + 4);
  ushort4 r0; r0.x = f2bf(u.x); r0.y = f2bf(u.y); r0.z = f2bf(u.z); r0.w = f2bf(u.w);
  ushort4 r1; r1.x = f2bf(v.x); r1.y = f2bf(v.y); r1.z = f2bf(v.z); r1.w = f2bf(v.w);
  *(ushort4*)(o + i) = r0;
  *(ushort4*)(o + i + 4) = r1;
}

// ---------------- bf16 MFMA GEMM: C[M x ncst] = A[M x 256] @ Wt^T, + bias, bf16 out ----------------
__global__ __launch_bounds__(256) void k_gemm(const ushort* __restrict__ A, const ushort* __restrict__ Bt,
                                              const float* __restrict__ bp, ushort* __restrict__ C,
                                              int M, int ldc, int ncst) {
  __shared__ ushort sA[128 * 64];
  __shared__ ushort sB[128 * 64];
  const int tid = threadIdx.x;
  const int lane = tid & 63;
  const int wave = tid >> 6;
  const int wm = wave >> 1, wn = wave & 1;
  const int bm = blockIdx.x, bn = blockIdx.y;

  f32x4 acc[4][4];
#pragma unroll
  for (int a = 0; a < 4; ++a)
#pragma unroll
    for (int b = 0; b < 4; ++b) acc[a][b] = (f32x4){0.f, 0.f, 0.f, 0.f};

  const char* Ab = (const char*)A;
  const char* Bb = (const char*)Bt;
  char* sAb = (char*)sA;
  char* sBb = (char*)sB;

  for (int kt = 0; kt < 4; ++kt) {
#pragma unroll
    for (int it = 0; it < 4; ++it) {
      int o = tid * 16 + it * 4096;
      int r = o >> 7, kb = o & 127;
      int ra = bm * 128 + r; if (ra >= M) ra = M - 1;
      gl2lds16(Ab + (size_t)ra * 512 + kt * 128 + kb, sAb + o);
      gl2lds16(Bb + (size_t)(bn * 128 + r) * 512 + kt * 128 + kb, sBb + o);
    }
    __syncthreads();
#pragma unroll
    for (int kk = 0; kk < 2; ++kk) {
      int kByte = kk * 64 + ((lane >> 4) << 4);
      bf16x8 af[4], bfr[4];
#pragma unroll
      for (int mi = 0; mi < 4; ++mi)
        af[mi] = *(const bf16x8*)(sAb + (wm * 64 + mi * 16 + (lane & 15)) * 128 + kByte);
#pragma unroll
      for (int ni = 0; ni < 4; ++ni)
        bfr[ni] = *(const bf16x8*)(sBb + (wn * 64 + ni * 16 + (lane & 15)) * 128 + kByte);
#pragma unroll
      for (int mi = 0; mi < 4; ++mi)
#pragma unroll
        for (int ni = 0; ni < 4; ++ni)
          acc[mi][ni] = __builtin_amdgcn_mfma_f32_16x16x32_bf16(af[mi], bfr[ni], acc[mi][ni], 0, 0, 0);
    }
    __syncthreads();
  }

  const int r0 = bm * 128 + wm * 64 + ((lane >> 4) << 2);
  const int c0 = bn * 128 + wn * 64 + (lane & 15);
#pragma unroll
  for (int ni = 0; ni < 4; ++ni) {
    int col = c0 + ni * 16;
    if (col >= ncst) continue;
    float bpv = bp[col];
#pragma unroll
    for (int mi = 0; mi < 4; ++mi)
#pragma unroll
      for (int i = 0; i < 4; ++i) {
        int row = r0 + mi * 16 + i;
        if (row < M) C[(size_t)row * ldc + col] = f2bf(acc[mi][ni][i] + bpv);
      }
  }
}

// ---------------- SpMM 256-dim: Y[i,:] = relu(sum w_e * H[col_e,:]), one wave/node ----------------
// 8-deep unrolled gathers (MLP), packed-f32 FMA, scalar loop bounds.
__global__ __launch_bounds__(256) void k_spmm256(const int* __restrict__ rp, const int2* __restrict__ cw,
                                                 const ushort* __restrict__ H, ushort* __restrict__ Y) {
  int node = blockIdx.x * 4 + (threadIdx.x >> 6);
  int lane = threadIdx.x & 63;
  int s = __builtin_amdgcn_readfirstlane(rp[node]);
  int e = __builtin_amdgcn_readfirstlane(rp[node + 1]);
  f32x2 a01 = {0.f, 0.f}, a23 = {0.f, 0.f};
  const char* Hb = (const char*)H + (lane << 3);  // this lane's 8B slot within a 512B row
  int i = s;
  for (; i + 8 <= e; i += 8) {
    int2 p0 = cw[i],     p1 = cw[i + 1], p2 = cw[i + 2], p3 = cw[i + 3];
    int2 p4 = cw[i + 4], p5 = cw[i + 5], p6 = cw[i + 6], p7 = cw[i + 7];
    uint2 g0 = *(const uint2*)(Hb + ((size_t)(unsigned)p0.x << 9));
    uint2 g1 = *(const uint2*)(Hb + ((size_t)(unsigned)p1.x << 9));
    uint2 g2 = *(const uint2*)(Hb + ((size_t)(unsigned)p2.x << 9));
    uint2 g3 = *(const uint2*)(Hb + ((size_t)(unsigned)p3.x << 9));
    uint2 g4 = *(const uint2*)(Hb + ((size_t)(unsigned)p4.x << 9));
    uint2 g5 = *(const uint2*)(Hb + ((size_t)(unsigned)p5.x << 9));
    uint2 g6 = *(const uint2*)(Hb + ((size_t)(unsigned)p6.x << 9));
    uint2 g7 = *(const uint2*)(Hb + ((size_t)(unsigned)p7.x << 9));
    f32x2 w0 = {__int_as_float(p0.y), __int_as_float(p0.y)};
    f32x2 w1 = {__int_as_float(p1.y), __int_as_float(p1.y)};
    f32x2 w2 = {__int_as_float(p2.y), __int_as_float(p2.y)};
    f32x2 w3 = {__int_as_float(p3.y), __int_as_float(p3.y)};
    f32x2 w4 = {__int_as_float(p4.y), __int_as_float(p4.y)};
    f32x2 w5 = {__int_as_float(p5.y), __int_as_float(p5.y)};
    f32x2 w6 = {__int_as_float(p6.y), __int_as_float(p6.y)};
    f32x2 w7 = {__int_as_float(p7.y), __int_as_float(p7.y)};
    a01 += w0 * bfpair(g0.x); a23 += w0 * bfpair(g0.y);
    a01 += w1 * bfpair(g1.x); a23 += w1 * bfpair(g1.y);
    a01 += w2 * bfpair(g2.x); a23 += w2 * bfpair(g2.y);
    a01 += w3 * bfpair(g3.x); a23 += w3 * bfpair(g3.y);
    a01 += w4 * bfpair(g4.x); a23 += w4 * bfpair(g4.y);
    a01 += w5 * bfpair(g5.x); a23 += w5 * bfpair(g5.y);
    a01 += w6 * bfpair(g6.x); a23 += w6 * bfpair(g6.y);
    a01 += w7 * bfpair(g7.x); a23 += w7 * bfpair(g7.y);
  }
  for (; i < e; ++i) {
    int2 p = cw[i];
    uint2 g = *(const uint2*)(Hb + ((size_t)(unsigned)p.x << 9));
    f32x2 wv = {__int_as_float(p.y), __int_as_float(p.y)};
    a01 += wv * bfpair(g.x);
    a23 += wv * bfpair(g.y);
  }
  ushort4 o;
  o.x = f2bf(fmaxf(a01.x, 0.f)); o.y = f2bf(fmaxf(a01.y, 0.f));
  o.z = f2bf(fmaxf(a23.x, 0.f)); o.w = f2bf(fmaxf(a23.y, 0.f));
  *(ushort4*)(Y + (size_t)node * 256 + (lane << 2)) = o;
}

// ---------------- SpMM 64-dim + fused log_softmax, fp32 out ----------------
__global__ __launch_bounds__(256) void k_spmm64(const int* __restrict__ rp, const int2* __restrict__ cw,
                                                const ushort* __restrict__ H, float* __restrict__ out) {
  int node = blockIdx.x * 4 + (threadIdx.x >> 6);
  int lane = threadIdx.x & 63;
  int s = __builtin_amdgcn_readfirstlane(rp[node]);
  int e = __builtin_amdgcn_readfirstlane(rp[node + 1]);
  float a = 0.f;
  int i = s;
  for (; i + 8 <= e; i += 8) {
    int2 p0 = cw[i],     p1 = cw[i + 1], p2 = cw[i + 2], p3 = cw[i + 3];
    int2 p4 = cw[i + 4], p5 = cw[i + 5], p6 = cw[i + 6], p7 = cw[i + 7];
    float h0 = bf2f(H[((size_t)(unsigned)p0.x << 6) + lane]);
    float h1 = bf2f(H[((size_t)(unsigned)p1.x << 6) + lane]);
    float h2 = bf2f(H[((size_t)(unsigned)p2.x << 6) + lane]);
    float h3 = bf2f(H[((size_t)(unsigned)p3.x << 6) + lane]);
    float h4 = bf2f(H[((size_t)(unsigned)p4.x << 6) + lane]);
    float h5 = bf2f(H[((size_t)(unsigned)p5.x << 6) + lane]);
    float h6 = bf2f(H[((size_t)(unsigned)p6.x << 6) + lane]);
    float h7 = bf2f(H[((size_t)(unsigned)p7.x << 6) + lane]);
    a += __int_as_float(p0.y) * h0 + __int_as_float(p1.y) * h1
       + __int_as_float(p2.y) * h2 + __int_as_float(p3.y) * h3;
    a += __int_as_float(p4.y) * h4 + __int_as_float(p5.y) * h5
       + __int_as_float(p6.y) * h6 + __int_as_float(p7.y) * h7;
  }
  for (; i < e; ++i) {
    int2 p = cw[i];
    a += __int_as_float(p.y) * bf2f(H[((size_t)(unsigned)p.x << 6) + lane]);
  }
  float mx = a;
#pragma unroll
  for (int o = 32; o > 0; o >>= 1) mx = fmaxf(mx, __shfl_xor(mx, o, 64));
  float ex = expf(a - mx);
  float sum = ex;
#pragma unroll
  for (int o = 32; o > 0; o >>= 1) sum += __shfl_xor(sum, o, 64);
  out[(size_t)node * 64 + lane] = (a - mx) - logf(sum);
}

extern "C" void kernel_launch(void* const* d_in, const int* in_sizes, int n_in,
                              void* d_out, int out_size, void* d_ws, size_t ws_size,
                              hipStream_t stream) {
  const float* x   = (const float*)d_in[0];
  const int* erow  = (const int*)d_in[1];
  const int* ecol  = (const int*)d_in[2];
  const float* ew  = (const float*)d_in[3];
  const float* W1  = (const float*)d_in[4];
  const float* b1  = (const float*)d_in[5];
  const float* g1  = (const float*)d_in[6];
  const float* be1 = (const float*)d_in[7];
  const float* m1  = (const float*)d_in[8];
  const float* v1  = (const float*)d_in[9];
  const float* W2  = (const float*)d_in[10];
  const float* b2  = (const float*)d_in[11];
  const float* g2  = (const float*)d_in[12];
  const float* be2 = (const float*)d_in[13];
  const float* m2  = (const float*)d_in[14];
  const float* v2  = (const float*)d_in[15];
  const float* W3  = (const float*)d_in[16];
  const float* b3  = (const float*)d_in[17];

  char* ws = (char*)d_ws;
  size_t off = 0;
  auto carve = [&](size_t bytes) -> void* {
    void* p = ws + off;
    off += (bytes + 511) & ~(size_t)511;
    return p;
  };
  int* bcnt   = (int*)carve((size_t)NBUCK * 4);
  int* bbase  = (int*)carve((size_t)NBUCK * 4);
  int* ghist  = (int*)carve((size_t)NBUCK * NCB * 4);
  int* rp     = (int*)carve((size_t)(NBUCK * 128 + 1) * 4);
  int2* cw    = (int2*)carve((size_t)NE * 8);
  ushort* W1t = (ushort*)carve(256 * 256 * 2);
  ushort* W2t = (ushort*)carve(256 * 256 * 2);
  ushort* W3t = (ushort*)carve(128 * 256 * 2);
  float* bp1  = (float*)carve(256 * 4);
  float* bp2  = (float*)carve(256 * 4);
  float* bp3  = (float*)carve(128 * 4);
  ushort* bufA = (ushort*)carve((size_t)NN * 256 * 2);
  ushort* bufB = (ushort*)carve((size_t)NN * 256 * 2);
  ushort* bufC = (ushort*)carve((size_t)NN * 64 * 2);
  if (off > ws_size) return;

  // bucket scratch aliases bufA (not live until k_f2bf8): NE*8 = 25.6MB <= 51.2MB
  int2* bdata = (int2*)bufA;

  // CSR build (two-pass block-local counting sort, no contended global atomics)
  hipMemsetAsync(bcnt, 0, (size_t)NBUCK * 4, stream);
  k_cnt<<<NCB, 256, 0, stream>>>(erow, ghist, bcnt);
  k_bscan<<<1, 1024, 0, stream>>>(bcnt, bbase);
  k_scan3<<<NBUCK, 64, 0, stream>>>(ghist, bbase);
  k_place<<<NCB, 256, 0, stream>>>(erow, ecol, ew, ghist, bdata);
  k_bsort<<<NBUCK, 256, 0, stream>>>(bcnt, bbase, bdata, cw, rp);

  // weights (BN folded, transposed, bf16)
  k_prep<<<256, 256, 0, stream>>>(W1, b1, g1, be1, m1, v1, W1t, bp1, 256);
  k_prep<<<256, 256, 0, stream>>>(W2, b2, g2, be2, m2, v2, W2t, bp2, 256);
  k_prep<<<128, 256, 0, stream>>>(W3, b3, nullptr, nullptr, nullptr, nullptr, W3t, bp3, 64);

  // x -> bf16
  k_f2bf8<<<(NN * 256) / (256 * 8), 256, 0, stream>>>(x, bufA);

  const int gm = (NN + 127) / 128;
  // layer 1
  k_gemm<<<dim3(gm, 2), 256, 0, stream>>>(bufA, W1t, bp1, bufB, NN, 256, 256);
  k_spmm256<<<NN / 4, 256, 0, stream>>>(rp, cw, bufB, bufA);
  // layer 2
  k_gemm<<<dim3(gm, 2), 256, 0, stream>>>(bufA, W2t, bp2, bufB, NN, 256, 256);
  k_spmm256<<<NN / 4, 256, 0, stream>>>(rp, cw, bufB, bufA);
  // output layer
  k_gemm<<<dim3(gm, 1), 256, 0, stream>>>(bufA, W3t, bp3, bufC, NN, 64, 64);
  k_spmm64<<<NN / 4, 256, 0, stream>>>(rp, cw, bufC, (float*)d_out);
}

// Round 6
// 767.657 us; speedup vs baseline: 1.0815x; 1.0214x over previous
//
#include <hip/hip_runtime.h>

#define NN 100000
#define NE 3200000
#define NBUCK 782   // ceil(NN/128)
#define EPB 8192
#define NCB 391     // ceil(NE/EPB)

typedef __attribute__((ext_vector_type(8))) short bf16x8;
typedef __attribute__((ext_vector_type(4))) float f32x4;
typedef __attribute__((ext_vector_type(2))) float f32x2;

__device__ __forceinline__ ushort f2bf(float f) {
  unsigned u = __builtin_bit_cast(unsigned, f);
  u = (u + 0x7FFFu + ((u >> 16) & 1u)) >> 16;
  return (ushort)u;
}
__device__ __forceinline__ float bf2f(ushort h) {
  return __builtin_bit_cast(float, ((unsigned)h) << 16);
}
__device__ __forceinline__ f32x2 bfpair(unsigned u) {
  f32x2 r;
  r.x = __builtin_bit_cast(float, u << 16);
  r.y = __builtin_bit_cast(float, u & 0xffff0000u);
  return r;
}
__device__ __forceinline__ void gl2lds16(const void* g, void* s) {
  __builtin_amdgcn_global_load_lds((const __attribute__((address_space(1))) void*)g,
                                   (__attribute__((address_space(3))) void*)s, 16, 0, 0);
}

// ---------------- CSR build: two-pass block-local counting sort ----------------
__global__ __launch_bounds__(256) void k_cnt(const int* __restrict__ row, int* __restrict__ ghist,
                                             int* __restrict__ bcnt) {
  __shared__ int h[NBUCK];
  int blk = blockIdx.x, tid = threadIdx.x;
  for (int i = tid; i < NBUCK; i += 256) h[i] = 0;
  __syncthreads();
  int lo = blk * EPB, hi = lo + EPB; if (hi > NE) hi = NE;
  for (int i = lo + tid * 4; i < hi; i += 1024) {
    int4 r = *(const int4*)(row + i);
    atomicAdd(&h[r.x >> 7], 1);
    atomicAdd(&h[r.y >> 7], 1);
    atomicAdd(&h[r.z >> 7], 1);
    atomicAdd(&h[r.w >> 7], 1);
  }
  __syncthreads();
  for (int i = tid; i < NBUCK; i += 256) {
    ghist[(size_t)i * NCB + blk] = h[i];
    if (h[i]) atomicAdd(&bcnt[i], h[i]);
  }
}

__global__ __launch_bounds__(1024) void k_bscan(const int* __restrict__ bcnt, int* __restrict__ bbase) {
  __shared__ int s[1024];
  int t = threadIdx.x;
  s[t] = (t < NBUCK) ? bcnt[t] : 0;
  __syncthreads();
  for (int o = 1; o < 1024; o <<= 1) {
    int v = (t >= o) ? s[t - o] : 0;
    __syncthreads();
    s[t] += v;
    __syncthreads();
  }
  if (t < NBUCK) bbase[t] = t ? s[t - 1] : 0;
}

__global__ __launch_bounds__(64) void k_scan3(int* __restrict__ ghist, const int* __restrict__ bbase) {
  int b = blockIdx.x, lane = threadIdx.x;
  int carry = bbase[b];
#pragma unroll
  for (int r = 0; r < 7; ++r) {
    int idx = r * 64 + lane;
    int v = (idx < NCB) ? ghist[(size_t)b * NCB + idx] : 0;
    int s = v;
#pragma unroll
    for (int o = 1; o < 64; o <<= 1) { int t = __shfl_up(s, o, 64); if (lane >= o) s += t; }
    if (idx < NCB) ghist[(size_t)b * NCB + idx] = carry + s - v;
    carry += __shfl(s, 63, 64);
  }
}

__global__ __launch_bounds__(256) void k_place(const int* __restrict__ row, const int* __restrict__ col,
                                               const float* __restrict__ w, const int* __restrict__ ghist,
                                               int2* __restrict__ bdata) {
  __shared__ int offs[NBUCK];
  int blk = blockIdx.x, tid = threadIdx.x;
  for (int i = tid; i < NBUCK; i += 256) offs[i] = ghist[(size_t)i * NCB + blk];
  __syncthreads();
  int lo = blk * EPB, hi = lo + EPB; if (hi > NE) hi = NE;
  for (int i = lo + tid * 4; i < hi; i += 1024) {
    int4 r = *(const int4*)(row + i);
    int4 c = *(const int4*)(col + i);
    float4 ww = *(const float4*)(w + i);
    int p;
    p = atomicAdd(&offs[r.x >> 7], 1); bdata[p] = make_int2(((r.x & 127) << 17) | c.x, __float_as_int(ww.x));
    p = atomicAdd(&offs[r.y >> 7], 1); bdata[p] = make_int2(((r.y & 127) << 17) | c.y, __float_as_int(ww.y));
    p = atomicAdd(&offs[r.z >> 7], 1); bdata[p] = make_int2(((r.z & 127) << 17) | c.z, __float_as_int(ww.z));
    p = atomicAdd(&offs[r.w >> 7], 1); bdata[p] = make_int2(((r.w & 127) << 17) | c.w, __float_as_int(ww.w));
  }
}

__global__ __launch_bounds__(256) void k_bsort(const int* __restrict__ bcnt, const int* __restrict__ bbase,
                                               const int2* __restrict__ bdata, int2* __restrict__ cw,
                                               int* __restrict__ rp) {
  __shared__ int sc[128], lpos[128];
  int b = blockIdx.x, t = threadIdx.x;
  int n = bcnt[b], base = bbase[b];
  if (t < 128) sc[t] = 0;
  __syncthreads();
  for (int i = t; i < n; i += 256) {
    int r = bdata[(size_t)base + i].x >> 17;
    atomicAdd(&sc[r], 1);
  }
  __syncthreads();
  for (int o = 1; o < 128; o <<= 1) {
    int v = (t < 128 && t >= o) ? sc[t - o] : 0;
    __syncthreads();
    if (t < 128) sc[t] += v;
    __syncthreads();
  }
  if (t < 128) {
    int excl = t ? sc[t - 1] : 0;
    lpos[t] = excl;
    int grow = b * 128 + t;
    if (grow <= NN) rp[grow] = base + excl;
  }
  __syncthreads();
  for (int i = t; i < n; i += 256) {
    int2 e = bdata[(size_t)base + i];
    int r = e.x >> 17;
    int p = atomicAdd(&lpos[r], 1);
    cw[base + p] = make_int2(e.x & 0x1FFFF, e.y);
  }
}

// ---------------- weight prep: fold BN, transpose to [N][K], cast bf16 ----------------
// swz=1: XOR-swizzle k-index (k ^ ((j&7)<<3)) so F's LDS tiles are bank-conflict-free
__global__ __launch_bounds__(256) void k_prep(const float* __restrict__ W, const float* __restrict__ b,
                                              const float* __restrict__ g, const float* __restrict__ be,
                                              const float* __restrict__ m, const float* __restrict__ v,
                                              ushort* __restrict__ Wt, float* __restrict__ bp, int Ncol,
                                              int swz) {
  int j = blockIdx.x, k = threadIdx.x;
  float s = 1.f, t = 0.f;
  if (g) { s = g[j] * rsqrtf(v[j] + 1e-5f); t = be[j] - m[j] * s; }
  float val = W[(size_t)k * Ncol + j] * s;
  if (k == 0) bp[j] = b[j] * s + t;
  int kk = swz ? (k ^ ((j & 7) << 3)) : k;
  Wt[(size_t)j * 256 + kk] = f2bf(val);
}

// ---------------- x fp32 -> bf16 ----------------
__global__ __launch_bounds__(256) void k_f2bf8(const float* __restrict__ x, ushort* __restrict__ o) {
  size_t i = ((size_t)blockIdx.x * 256 + threadIdx.x) * 8;
  float4 u = *(const float4*)(x + i);
  float4 v = *(const float4*)(x + i + 4);
  ushort4 r0; r0.x = f2bf(u.x); r0.y = f2bf(u.y); r0.z = f2bf(u.z); r0.w = f2bf(u.w);
  ushort4 r1; r1.x = f2bf(v.x); r1.y = f2bf(v.y); r1.z = f2bf(v.z); r1.w = f2bf(v.w);
  *(ushort4*)(o + i) = r0;
  *(ushort4*)(o + i + 4) = r1;
}

// ---------------- bf16 MFMA GEMM (layer 1 only): C = A[M x 256] @ Wt^T + bias ----------------
__global__ __launch_bounds__(256) void k_gemm(const ushort* __restrict__ A, const ushort* __restrict__ Bt,
                                              const float* __restrict__ bp, ushort* __restrict__ C,
                                              int M, int ldc, int ncst) {
  __shared__ ushort sA[128 * 64];
  __shared__ ushort sB[128 * 64];
  const int tid = threadIdx.x;
  const int lane = tid & 63;
  const int wave = tid >> 6;
  const int wm = wave >> 1, wn = wave & 1;
  const int bm = blockIdx.x, bn = blockIdx.y;

  f32x4 acc[4][4];
#pragma unroll
  for (int a = 0; a < 4; ++a)
#pragma unroll
    for (int b = 0; b < 4; ++b) acc[a][b] = (f32x4){0.f, 0.f, 0.f, 0.f};

  const char* Ab = (const char*)A;
  const char* Bb = (const char*)Bt;
  char* sAb = (char*)sA;
  char* sBb = (char*)sB;

  for (int kt = 0; kt < 4; ++kt) {
#pragma unroll
    for (int it = 0; it < 4; ++it) {
      int o = tid * 16 + it * 4096;
      int r = o >> 7, kb = o & 127;
      int ra = bm * 128 + r; if (ra >= M) ra = M - 1;
      gl2lds16(Ab + (size_t)ra * 512 + kt * 128 + kb, sAb + o);
      gl2lds16(Bb + (size_t)(bn * 128 + r) * 512 + kt * 128 + kb, sBb + o);
    }
    __syncthreads();
#pragma unroll
    for (int kk = 0; kk < 2; ++kk) {
      int kByte = kk * 64 + ((lane >> 4) << 4);
      bf16x8 af[4], bfr[4];
#pragma unroll
      for (int mi = 0; mi < 4; ++mi)
        af[mi] = *(const bf16x8*)(sAb + (wm * 64 + mi * 16 + (lane & 15)) * 128 + kByte);
#pragma unroll
      for (int ni = 0; ni < 4; ++ni)
        bfr[ni] = *(const bf16x8*)(sBb + (wn * 64 + ni * 16 + (lane & 15)) * 128 + kByte);
#pragma unroll
      for (int mi = 0; mi < 4; ++mi)
#pragma unroll
        for (int ni = 0; ni < 4; ++ni)
          acc[mi][ni] = __builtin_amdgcn_mfma_f32_16x16x32_bf16(af[mi], bfr[ni], acc[mi][ni], 0, 0, 0);
    }
    __syncthreads();
  }

  const int r0 = bm * 128 + wm * 64 + ((lane >> 4) << 2);
  const int c0 = bn * 128 + wn * 64 + (lane & 15);
#pragma unroll
  for (int ni = 0; ni < 4; ++ni) {
    int col = c0 + ni * 16;
    if (col >= ncst) continue;
    float bpv = bp[col];
#pragma unroll
    for (int mi = 0; mi < 4; ++mi)
#pragma unroll
      for (int i = 0; i < 4; ++i) {
        int row = r0 + mi * 16 + i;
        if (row < M) C[(size_t)row * ldc + col] = f2bf(acc[mi][ni][i] + bpv);
      }
  }
}

// gather-accumulate one batch of up to 16 edges (predicated tail, fully pipelined)
__device__ __forceinline__ void gacc16(const int2* __restrict__ cw, int i, int rem,
                                       const char* __restrict__ Hb, f32x2& a01, f32x2& a23) {
  int2 p[16]; uint2 g[16];
#pragma unroll
  for (int u = 0; u < 16; ++u) p[u] = cw[i + (u < rem ? u : 0)];
#pragma unroll
  for (int u = 0; u < 16; ++u) g[u] = *(const uint2*)(Hb + ((size_t)(unsigned)p[u].x << 9));
#pragma unroll
  for (int u = 0; u < 16; ++u) {
    float wf = (u < rem) ? __int_as_float(p[u].y) : 0.f;
    f32x2 wv = {wf, wf};
    a01 += wv * bfpair(g[u].x);
    a23 += wv * bfpair(g[u].y);
  }
}

// ---------------- FUSED: Zout = relu(P @ Zin) @ Wt^T + bias ----------------
// Block = 64 nodes. Gather phase -> 32KB LDS H-tile (XOR-swizzled), then MFMA vs W (pre-swizzled).
template <int NOUT>
__global__ __launch_bounds__(256) void k_fspmm(const int* __restrict__ rp, const int2* __restrict__ cw,
                                               const ushort* __restrict__ Zin, const ushort* __restrict__ Wt,
                                               const float* __restrict__ bp, ushort* __restrict__ Zout) {
  __shared__ ushort sH[64 * 256];       // 32KB
  __shared__ ushort sW[NOUT * 64];      // 32KB (NOUT=256) or 8KB (NOUT=64)
  const int tid = threadIdx.x;
  const int lane = tid & 63;
  const int w = tid >> 6;
  const int blk = blockIdx.x;
  char* sHb = (char*)sH;
  char* sWb = (char*)sW;

  // ---- gather phase: each wave produces 16 H-tile rows ----
  const char* Hb = (const char*)Zin + (lane << 3);
  for (int j = 0; j < 16; ++j) {
    int local = w * 16 + j;
    int node = blk * 64 + local;
    if (node < NN) {
      int s = __builtin_amdgcn_readfirstlane(rp[node]);
      int e = __builtin_amdgcn_readfirstlane(rp[node + 1]);
      f32x2 a01 = {0.f, 0.f}, a23 = {0.f, 0.f};
      int i = s;
      for (; i + 16 <= e; i += 16) gacc16(cw, i, 16, Hb, a01, a23);
      int rem = e - i;
      if (rem) gacc16(cw, i, rem, Hb, a01, a23);
      ushort4 o;
      o.x = f2bf(fmaxf(a01.x, 0.f)); o.y = f2bf(fmaxf(a01.y, 0.f));
      o.z = f2bf(fmaxf(a23.x, 0.f)); o.w = f2bf(fmaxf(a23.y, 0.f));
      int byte = local * 512 + ((lane << 3) ^ ((local & 7) << 4));
      *(ushort4*)(sHb + byte) = o;
    }
  }

  // ---- MFMA phase: C[64 x NOUT] = Htile @ Wt^T ----
  constexpr int NF = (NOUT == 256) ? 4 : 1;     // n-frags per wave
  constexpr int ITS = (NOUT * 64 * 2) / 4096;   // gl2lds insts per K-step: 8 or 2
  const int colbase = (NOUT == 256) ? w * 64 : w * 16;
  f32x4 acc[4][NF];
#pragma unroll
  for (int a = 0; a < 4; ++a)
#pragma unroll
    for (int b = 0; b < NF; ++b) acc[a][b] = (f32x4){0.f, 0.f, 0.f, 0.f};

  for (int kt = 0; kt < 4; ++kt) {
#pragma unroll
    for (int it = 0; it < ITS; ++it) {
      int o = tid * 16 + it * 4096;
      int ccol = o >> 7, kb = o & 127;
      gl2lds16((const char*)Wt + (size_t)ccol * 512 + kt * 128 + kb, sWb + o);
    }
    __syncthreads();   // gathers (first iter) + W stage complete
#pragma unroll
    for (int kk = 0; kk < 2; ++kk) {
      int kByte = kk * 64 + ((lane >> 4) << 4);
      bf16x8 af[4], bfr[NF];
#pragma unroll
      for (int mi = 0; mi < 4; ++mi) {
        int r = mi * 16 + (lane & 15);
        af[mi] = *(const bf16x8*)(sHb + r * 512 + ((kt * 128 + kByte) ^ ((r & 7) << 4)));
      }
#pragma unroll
      for (int ni = 0; ni < NF; ++ni) {
        int c = colbase + ni * 16 + (lane & 15);
        bfr[ni] = *(const bf16x8*)(sWb + c * 128 + (kByte ^ ((c & 7) << 4)));
      }
#pragma unroll
      for (int mi = 0; mi < 4; ++mi)
#pragma unroll
        for (int ni = 0; ni < NF; ++ni)
          acc[mi][ni] = __builtin_amdgcn_mfma_f32_16x16x32_bf16(af[mi], bfr[ni], acc[mi][ni], 0, 0, 0);
    }
    __syncthreads();   // reads done before next W stage
  }

  // ---- epilogue: + bias, bf16 store ----
  const int r0 = (lane >> 4) << 2;
#pragma unroll
  for (int ni = 0; ni < NF; ++ni) {
    int col = colbase + ni * 16 + (lane & 15);
    float bpv = bp[col];
#pragma unroll
    for (int mi = 0; mi < 4; ++mi)
#pragma unroll
      for (int i = 0; i < 4; ++i) {
        int row = blk * 64 + mi * 16 + r0 + i;
        if (row < NN) Zout[(size_t)row * NOUT + col] = f2bf(acc[mi][ni][i] + bpv);
      }
  }
}

// ---------------- SpMM 64-dim + fused log_softmax, fp32 out ----------------
__device__ __forceinline__ void gacc64(const int2* __restrict__ cw, int i, int rem,
                                       const ushort* __restrict__ H, int lane, float& a) {
  int2 p[16]; float h[16];
#pragma unroll
  for (int u = 0; u < 16; ++u) p[u] = cw[i + (u < rem ? u : 0)];
#pragma unroll
  for (int u = 0; u < 16; ++u) h[u] = bf2f(H[((size_t)(unsigned)p[u].x << 6) + lane]);
#pragma unroll
  for (int u = 0; u < 16; ++u) a += ((u < rem) ? __int_as_float(p[u].y) : 0.f) * h[u];
}

__global__ __launch_bounds__(256) void k_spmm64(const int* __restrict__ rp, const int2* __restrict__ cw,
                                                const ushort* __restrict__ H, float* __restrict__ out) {
  int node = blockIdx.x * 4 + (threadIdx.x >> 6);
  int lane = threadIdx.x & 63;
  int s = __builtin_amdgcn_readfirstlane(rp[node]);
  int e = __builtin_amdgcn_readfirstlane(rp[node + 1]);
  float a = 0.f;
  int i = s;
  for (; i + 16 <= e; i += 16) gacc64(cw, i, 16, H, lane, a);
  int rem = e - i;
  if (rem) gacc64(cw, i, rem, H, lane, a);
  float mx = a;
#pragma unroll
  for (int o = 32; o > 0; o >>= 1) mx = fmaxf(mx, __shfl_xor(mx, o, 64));
  float ex = expf(a - mx);
  float sum = ex;
#pragma unroll
  for (int o = 32; o > 0; o >>= 1) sum += __shfl_xor(sum, o, 64);
  out[(size_t)node * 64 + lane] = (a - mx) - logf(sum);
}

extern "C" void kernel_launch(void* const* d_in, const int* in_sizes, int n_in,
                              void* d_out, int out_size, void* d_ws, size_t ws_size,
                              hipStream_t stream) {
  const float* x   = (const float*)d_in[0];
  const int* erow  = (const int*)d_in[1];
  const int* ecol  = (const int*)d_in[2];
  const float* ew  = (const float*)d_in[3];
  const float* W1  = (const float*)d_in[4];
  const float* b1  = (const float*)d_in[5];
  const float* g1  = (const float*)d_in[6];
  const float* be1 = (const float*)d_in[7];
  const float* m1  = (const float*)d_in[8];
  const float* v1  = (const float*)d_in[9];
  const float* W2  = (const float*)d_in[10];
  const float* b2  = (const float*)d_in[11];
  const float* g2  = (const float*)d_in[12];
  const float* be2 = (const float*)d_in[13];
  const float* m2  = (const float*)d_in[14];
  const float* v2  = (const float*)d_in[15];
  const float* W3  = (const float*)d_in[16];
  const float* b3  = (const float*)d_in[17];

  char* ws = (char*)d_ws;
  size_t off = 0;
  auto carve = [&](size_t bytes) -> void* {
    void* p = ws + off;
    off += (bytes + 511) & ~(size_t)511;
    return p;
  };
  int* bcnt   = (int*)carve((size_t)NBUCK * 4);
  int* bbase  = (int*)carve((size_t)NBUCK * 4);
  int* ghist  = (int*)carve((size_t)NBUCK * NCB * 4);
  int* rp     = (int*)carve((size_t)(NBUCK * 128 + 1) * 4);
  int2* cw    = (int2*)carve((size_t)NE * 8);
  ushort* W1t = (ushort*)carve(256 * 256 * 2);
  ushort* W2t = (ushort*)carve(256 * 256 * 2);
  ushort* W3t = (ushort*)carve(64 * 256 * 2);
  float* bp1  = (float*)carve(256 * 4);
  float* bp2  = (float*)carve(256 * 4);
  float* bp3  = (float*)carve(64 * 4);
  ushort* bufA = (ushort*)carve((size_t)NN * 256 * 2);
  ushort* bufB = (ushort*)carve((size_t)NN * 256 * 2);
  ushort* bufC = (ushort*)carve((size_t)NN * 64 * 2);
  if (off > ws_size) return;

  // bucket scratch aliases bufA (not live until k_f2bf8): NE*8 = 25.6MB <= 51.2MB
  int2* bdata = (int2*)bufA;

  // CSR build
  hipMemsetAsync(bcnt, 0, (size_t)NBUCK * 4, stream);
  k_cnt<<<NCB, 256, 0, stream>>>(erow, ghist, bcnt);
  k_bscan<<<1, 1024, 0, stream>>>(bcnt, bbase);
  k_scan3<<<NBUCK, 64, 0, stream>>>(ghist, bbase);
  k_place<<<NCB, 256, 0, stream>>>(erow, ecol, ew, ghist, bdata);
  k_bsort<<<NBUCK, 256, 0, stream>>>(bcnt, bbase, bdata, cw, rp);

  // weights: W1 linear (for k_gemm), W2/W3 swizzled (for k_fspmm)
  k_prep<<<256, 256, 0, stream>>>(W1, b1, g1, be1, m1, v1, W1t, bp1, 256, 0);
  k_prep<<<256, 256, 0, stream>>>(W2, b2, g2, be2, m2, v2, W2t, bp2, 256, 1);
  k_prep<<<64, 256, 0, stream>>>(W3, b3, nullptr, nullptr, nullptr, nullptr, W3t, bp3, 64, 1);

  // x -> bf16
  k_f2bf8<<<(NN * 256) / (256 * 8), 256, 0, stream>>>(x, bufA);

  const int gm = (NN + 127) / 128;
  const int gf = (NN + 63) / 64;   // 1563
  // layer 1: z1 = x @ W1' + b1'
  k_gemm<<<dim3(gm, 2), 256, 0, stream>>>(bufA, W1t, bp1, bufB, NN, 256, 256);
  // layer 2 fused: z2 = relu(P @ z1) @ W2' + b2'
  k_fspmm<256><<<gf, 256, 0, stream>>>(rp, cw, bufB, W2t, bp2, bufA);
  // layer 3 fused: z3 = relu(P @ z2) @ W3 + b3
  k_fspmm<64><<<gf, 256, 0, stream>>>(rp, cw, bufA, W3t, bp3, bufC);
  // out = log_softmax(P @ z3)
  k_spmm64<<<NN / 4, 256, 0, stream>>>(rp, cw, bufC, (float*)d_out);
}

// Round 7
// 755.855 us; speedup vs baseline: 1.0984x; 1.0156x over previous
//
#include <hip/hip_runtime.h>

#define NN 100000
#define NE 3200000
#define NBUCK 782   // ceil(NN/128)
#define EPB 8192
#define NCB 391     // ceil(NE/EPB)

typedef __attribute__((ext_vector_type(8))) short bf16x8;
typedef __attribute__((ext_vector_type(4))) float f32x4;
typedef __attribute__((ext_vector_type(2))) float f32x2;

__device__ __forceinline__ ushort f2bf(float f) {
  unsigned u = __builtin_bit_cast(unsigned, f);
  u = (u + 0x7FFFu + ((u >> 16) & 1u)) >> 16;
  return (ushort)u;
}
__device__ __forceinline__ float bf2f(ushort h) {
  return __builtin_bit_cast(float, ((unsigned)h) << 16);
}
__device__ __forceinline__ f32x2 bfpair(unsigned u) {
  f32x2 r;
  r.x = __builtin_bit_cast(float, u << 16);
  r.y = __builtin_bit_cast(float, u & 0xffff0000u);
  return r;
}
__device__ __forceinline__ void gl2lds16(const void* g, void* s) {
  __builtin_amdgcn_global_load_lds((const __attribute__((address_space(1))) void*)g,
                                   (__attribute__((address_space(3))) void*)s, 16, 0, 0);
}

// ---------------- CSR build: two-pass block-local counting sort ----------------
__global__ __launch_bounds__(256) void k_cnt(const int* __restrict__ row, int* __restrict__ ghist,
                                             int* __restrict__ bcnt) {
  __shared__ int h[NBUCK];
  int blk = blockIdx.x, tid = threadIdx.x;
  for (int i = tid; i < NBUCK; i += 256) h[i] = 0;
  __syncthreads();
  int lo = blk * EPB, hi = lo + EPB; if (hi > NE) hi = NE;
  for (int i = lo + tid * 4; i < hi; i += 1024) {
    int4 r = *(const int4*)(row + i);
    atomicAdd(&h[r.x >> 7], 1);
    atomicAdd(&h[r.y >> 7], 1);
    atomicAdd(&h[r.z >> 7], 1);
    atomicAdd(&h[r.w >> 7], 1);
  }
  __syncthreads();
  for (int i = tid; i < NBUCK; i += 256) {
    ghist[(size_t)i * NCB + blk] = h[i];
    if (h[i]) atomicAdd(&bcnt[i], h[i]);
  }
}

__global__ __launch_bounds__(1024) void k_bscan(const int* __restrict__ bcnt, int* __restrict__ bbase) {
  __shared__ int s[1024];
  int t = threadIdx.x;
  s[t] = (t < NBUCK) ? bcnt[t] : 0;
  __syncthreads();
  for (int o = 1; o < 1024; o <<= 1) {
    int v = (t >= o) ? s[t - o] : 0;
    __syncthreads();
    s[t] += v;
    __syncthreads();
  }
  if (t < NBUCK) bbase[t] = t ? s[t - 1] : 0;
}

__global__ __launch_bounds__(64) void k_scan3(int* __restrict__ ghist, const int* __restrict__ bbase) {
  int b = blockIdx.x, lane = threadIdx.x;
  int carry = bbase[b];
#pragma unroll
  for (int r = 0; r < 7; ++r) {
    int idx = r * 64 + lane;
    int v = (idx < NCB) ? ghist[(size_t)b * NCB + idx] : 0;
    int s = v;
#pragma unroll
    for (int o = 1; o < 64; o <<= 1) { int t = __shfl_up(s, o, 64); if (lane >= o) s += t; }
    if (idx < NCB) ghist[(size_t)b * NCB + idx] = carry + s - v;
    carry += __shfl(s, 63, 64);
  }
}

__global__ __launch_bounds__(256) void k_place(const int* __restrict__ row, const int* __restrict__ col,
                                               const float* __restrict__ w, const int* __restrict__ ghist,
                                               int2* __restrict__ bdata) {
  __shared__ int offs[NBUCK];
  int blk = blockIdx.x, tid = threadIdx.x;
  for (int i = tid; i < NBUCK; i += 256) offs[i] = ghist[(size_t)i * NCB + blk];
  __syncthreads();
  int lo = blk * EPB, hi = lo + EPB; if (hi > NE) hi = NE;
  for (int i = lo + tid * 4; i < hi; i += 1024) {
    int4 r = *(const int4*)(row + i);
    int4 c = *(const int4*)(col + i);
    float4 ww = *(const float4*)(w + i);
    int p;
    p = atomicAdd(&offs[r.x >> 7], 1); bdata[p] = make_int2(((r.x & 127) << 17) | c.x, __float_as_int(ww.x));
    p = atomicAdd(&offs[r.y >> 7], 1); bdata[p] = make_int2(((r.y & 127) << 17) | c.y, __float_as_int(ww.y));
    p = atomicAdd(&offs[r.z >> 7], 1); bdata[p] = make_int2(((r.z & 127) << 17) | c.z, __float_as_int(ww.z));
    p = atomicAdd(&offs[r.w >> 7], 1); bdata[p] = make_int2(((r.w & 127) << 17) | c.w, __float_as_int(ww.w));
  }
}

__global__ __launch_bounds__(256) void k_bsort(const int* __restrict__ bcnt, const int* __restrict__ bbase,
                                               const int2* __restrict__ bdata, int2* __restrict__ cw,
                                               int* __restrict__ rp) {
  __shared__ int sc[128], lpos[128];
  int b = blockIdx.x, t = threadIdx.x;
  int n = bcnt[b], base = bbase[b];
  if (t < 128) sc[t] = 0;
  __syncthreads();
  for (int i = t; i < n; i += 256) {
    int r = bdata[(size_t)base + i].x >> 17;
    atomicAdd(&sc[r], 1);
  }
  __syncthreads();
  for (int o = 1; o < 128; o <<= 1) {
    int v = (t < 128 && t >= o) ? sc[t - o] : 0;
    __syncthreads();
    if (t < 128) sc[t] += v;
    __syncthreads();
  }
  if (t < 128) {
    int excl = t ? sc[t - 1] : 0;
    lpos[t] = excl;
    int grow = b * 128 + t;
    if (grow <= NN) rp[grow] = base + excl;
  }
  __syncthreads();
  for (int i = t; i < n; i += 256) {
    int2 e = bdata[(size_t)base + i];
    int r = e.x >> 17;
    int p = atomicAdd(&lpos[r], 1);
    cw[base + p] = make_int2(e.x & 0x1FFFF, e.y);
  }
}

// ---------------- weight prep: fold BN, transpose to [N][K], cast bf16 ----------------
// rows j >= Ncol zero-padded (so a 128-wide B-tile never reads garbage)
__global__ __launch_bounds__(256) void k_prep(const float* __restrict__ W, const float* __restrict__ b,
                                              const float* __restrict__ g, const float* __restrict__ be,
                                              const float* __restrict__ m, const float* __restrict__ v,
                                              ushort* __restrict__ Wt, float* __restrict__ bp, int Ncol) {
  int j = blockIdx.x, k = threadIdx.x;
  float val = 0.f;
  if (j < Ncol) {
    float s = 1.f, t = 0.f;
    if (g) { s = g[j] * rsqrtf(v[j] + 1e-5f); t = be[j] - m[j] * s; }
    val = W[(size_t)k * Ncol + j] * s;
    if (k == 0) bp[j] = b[j] * s + t;
  } else if (k == 0) bp[j] = 0.f;
  Wt[(size_t)j * 256 + k] = f2bf(val);
}

// ---------------- x fp32 -> bf16 ----------------
__global__ __launch_bounds__(256) void k_f2bf8(const float* __restrict__ x, ushort* __restrict__ o) {
  size_t i = ((size_t)blockIdx.x * 256 + threadIdx.x) * 8;
  float4 u = *(const float4*)(x + i);
  float4 v = *(const float4*)(x + i + 4);
  ushort4 r0; r0.x = f2bf(u.x); r0.y = f2bf(u.y); r0.z = f2bf(u.z); r0.w = f2bf(u.w);
  ushort4 r1; r1.x = f2bf(v.x); r1.y = f2bf(v.y); r1.z = f2bf(v.z); r1.w = f2bf(v.w);
  *(ushort4*)(o + i) = r0;
  *(ushort4*)(o + i + 4) = r1;
}

// ---------------- bf16 MFMA GEMM: C[M x ncst] = A[M x 256] @ Wt^T, + bias, bf16 out ----------------
__global__ __launch_bounds__(256) void k_gemm(const ushort* __restrict__ A, const ushort* __restrict__ Bt,
                                              const float* __restrict__ bp, ushort* __restrict__ C,
                                              int M, int ldc, int ncst) {
  __shared__ ushort sA[128 * 64];
  __shared__ ushort sB[128 * 64];
  const int tid = threadIdx.x;
  const int lane = tid & 63;
  const int wave = tid >> 6;
  const int wm = wave >> 1, wn = wave & 1;
  const int bm = blockIdx.x, bn = blockIdx.y;

  f32x4 acc[4][4];
#pragma unroll
  for (int a = 0; a < 4; ++a)
#pragma unroll
    for (int b = 0; b < 4; ++b) acc[a][b] = (f32x4){0.f, 0.f, 0.f, 0.f};

  const char* Ab = (const char*)A;
  const char* Bb = (const char*)Bt;
  char* sAb = (char*)sA;
  char* sBb = (char*)sB;

  for (int kt = 0; kt < 4; ++kt) {
#pragma unroll
    for (int it = 0; it < 4; ++it) {
      int o = tid * 16 + it * 4096;
      int r = o >> 7, kb = o & 127;
      int ra = bm * 128 + r; if (ra >= M) ra = M - 1;
      gl2lds16(Ab + (size_t)ra * 512 + kt * 128 + kb, sAb + o);
      gl2lds16(Bb + (size_t)(bn * 128 + r) * 512 + kt * 128 + kb, sBb + o);
    }
    __syncthreads();
#pragma unroll
    for (int kk = 0; kk < 2; ++kk) {
      int kByte = kk * 64 + ((lane >> 4) << 4);
      bf16x8 af[4], bfr[4];
#pragma unroll
      for (int mi = 0; mi < 4; ++mi)
        af[mi] = *(const bf16x8*)(sAb + (wm * 64 + mi * 16 + (lane & 15)) * 128 + kByte);
#pragma unroll
      for (int ni = 0; ni < 4; ++ni)
        bfr[ni] = *(const bf16x8*)(sBb + (wn * 64 + ni * 16 + (lane & 15)) * 128 + kByte);
#pragma unroll
      for (int mi = 0; mi < 4; ++mi)
#pragma unroll
        for (int ni = 0; ni < 4; ++ni)
          acc[mi][ni] = __builtin_amdgcn_mfma_f32_16x16x32_bf16(af[mi], bfr[ni], acc[mi][ni], 0, 0, 0);
    }
    __syncthreads();
  }

  const int r0 = bm * 128 + wm * 64 + ((lane >> 4) << 2);
  const int c0 = bn * 128 + wn * 64 + (lane & 15);
#pragma unroll
  for (int ni = 0; ni < 4; ++ni) {
    int col = c0 + ni * 16;
    if (col >= ncst) continue;
    float bpv = bp[col];
#pragma unroll
    for (int mi = 0; mi < 4; ++mi)
#pragma unroll
      for (int i = 0; i < 4; ++i) {
        int row = r0 + mi * 16 + i;
        if (row < M) C[(size_t)row * ldc + col] = f2bf(acc[mi][ni][i] + bpv);
      }
  }
}

// gather-accumulate one batch of up to 16 edges (predicated tail, fully pipelined)
__device__ __forceinline__ void gacc16(const int2* __restrict__ cw, int i, int rem,
                                       const char* __restrict__ Hb, f32x2& a01, f32x2& a23) {
  int2 p[16]; uint2 g[16];
#pragma unroll
  for (int u = 0; u < 16; ++u) p[u] = cw[i + (u < rem ? u : 0)];
#pragma unroll
  for (int u = 0; u < 16; ++u) g[u] = *(const uint2*)(Hb + ((size_t)(unsigned)p[u].x << 9));
#pragma unroll
  for (int u = 0; u < 16; ++u) {
    float wf = (u < rem) ? __int_as_float(p[u].y) : 0.f;
    f32x2 wv = {wf, wf};
    a01 += wv * bfpair(g[u].x);
    a23 += wv * bfpair(g[u].y);
  }
}

// ---------------- SpMM 256-dim: Y[i,:] = relu(sum w_e * H[col_e,:]), one wave/node ----------------
__global__ __launch_bounds__(256) void k_spmm256(const int* __restrict__ rp, const int2* __restrict__ cw,
                                                 const ushort* __restrict__ H, ushort* __restrict__ Y) {
  int node = blockIdx.x * 4 + (threadIdx.x >> 6);
  int lane = threadIdx.x & 63;
  int s = __builtin_amdgcn_readfirstlane(rp[node]);
  int e = __builtin_amdgcn_readfirstlane(rp[node + 1]);
  f32x2 a01 = {0.f, 0.f}, a23 = {0.f, 0.f};
  const char* Hb = (const char*)H + (lane << 3);
  int i = s;
  for (; i + 16 <= e; i += 16) gacc16(cw, i, 16, Hb, a01, a23);
  int rem = e - i;
  if (rem) gacc16(cw, i, rem, Hb, a01, a23);
  ushort4 o;
  o.x = f2bf(fmaxf(a01.x, 0.f)); o.y = f2bf(fmaxf(a01.y, 0.f));
  o.z = f2bf(fmaxf(a23.x, 0.f)); o.w = f2bf(fmaxf(a23.y, 0.f));
  *(ushort4*)(Y + (size_t)node * 256 + (lane << 2)) = o;
}

// ---------------- SpMM 64-dim + fused log_softmax, fp32 out ----------------
__device__ __forceinline__ void gacc64(const int2* __restrict__ cw, int i, int rem,
                                       const ushort* __restrict__ H, int lane, float& a) {
  int2 p[16]; float h[16];
#pragma unroll
  for (int u = 0; u < 16; ++u) p[u] = cw[i + (u < rem ? u : 0)];
#pragma unroll
  for (int u = 0; u < 16; ++u) h[u] = bf2f(H[((size_t)(unsigned)p[u].x << 6) + lane]);
#pragma unroll
  for (int u = 0; u < 16; ++u) a += ((u < rem) ? __int_as_float(p[u].y) : 0.f) * h[u];
}

__global__ __launch_bounds__(256) void k_spmm64(const int* __restrict__ rp, const int2* __restrict__ cw,
                                                const ushort* __restrict__ H, float* __restrict__ out) {
  int node = blockIdx.x * 4 + (threadIdx.x >> 6);
  int lane = threadIdx.x & 63;
  int s = __builtin_amdgcn_readfirstlane(rp[node]);
  int e = __builtin_amdgcn_readfirstlane(rp[node + 1]);
  float a = 0.f;
  int i = s;
  for (; i + 16 <= e; i += 16) gacc64(cw, i, 16, H, lane, a);
  int rem = e - i;
  if (rem) gacc64(cw, i, rem, H, lane, a);
  float mx = a;
#pragma unroll
  for (int o = 32; o > 0; o >>= 1) mx = fmaxf(mx, __shfl_xor(mx, o, 64));
  float ex = expf(a - mx);
  float sum = ex;
#pragma unroll
  for (int o = 32; o > 0; o >>= 1) sum += __shfl_xor(sum, o, 64);
  out[(size_t)node * 64 + lane] = (a - mx) - logf(sum);
}

extern "C" void kernel_launch(void* const* d_in, const int* in_sizes, int n_in,
                              void* d_out, int out_size, void* d_ws, size_t ws_size,
                              hipStream_t stream) {
  const float* x   = (const float*)d_in[0];
  const int* erow  = (const int*)d_in[1];
  const int* ecol  = (const int*)d_in[2];
  const float* ew  = (const float*)d_in[3];
  const float* W1  = (const float*)d_in[4];
  const float* b1  = (const float*)d_in[5];
  const float* g1  = (const float*)d_in[6];
  const float* be1 = (const float*)d_in[7];
  const float* m1  = (const float*)d_in[8];
  const float* v1  = (const float*)d_in[9];
  const float* W2  = (const float*)d_in[10];
  const float* b2  = (const float*)d_in[11];
  const float* g2  = (const float*)d_in[12];
  const float* be2 = (const float*)d_in[13];
  const float* m2  = (const float*)d_in[14];
  const float* v2  = (const float*)d_in[15];
  const float* W3  = (const float*)d_in[16];
  const float* b3  = (const float*)d_in[17];

  char* ws = (char*)d_ws;
  size_t off = 0;
  auto carve = [&](size_t bytes) -> void* {
    void* p = ws + off;
    off += (bytes + 511) & ~(size_t)511;
    return p;
  };
  int* bcnt   = (int*)carve((size_t)NBUCK * 4);
  int* bbase  = (int*)carve((size_t)NBUCK * 4);
  int* ghist  = (int*)carve((size_t)NBUCK * NCB * 4);
  int* rp     = (int*)carve((size_t)(NBUCK * 128 + 1) * 4);
  int2* cw    = (int2*)carve((size_t)NE * 8);
  ushort* W1t = (ushort*)carve(256 * 256 * 2);
  ushort* W2t = (ushort*)carve(256 * 256 * 2);
  ushort* W3t = (ushort*)carve(128 * 256 * 2);
  float* bp1  = (float*)carve(256 * 4);
  float* bp2  = (float*)carve(256 * 4);
  float* bp3  = (float*)carve(128 * 4);
  ushort* bufA = (ushort*)carve((size_t)NN * 256 * 2);
  ushort* bufB = (ushort*)carve((size_t)NN * 256 * 2);
  ushort* bufC = (ushort*)carve((size_t)NN * 64 * 2);
  if (off > ws_size) return;

  // bucket scratch aliases bufA (not live until k_f2bf8): NE*8 = 25.6MB <= 51.2MB
  int2* bdata = (int2*)bufA;

  // CSR build (two-pass block-local counting sort, no contended global atomics)
  hipMemsetAsync(bcnt, 0, (size_t)NBUCK * 4, stream);
  k_cnt<<<NCB, 256, 0, stream>>>(erow, ghist, bcnt);
  k_bscan<<<1, 1024, 0, stream>>>(bcnt, bbase);
  k_scan3<<<NBUCK, 64, 0, stream>>>(ghist, bbase);
  k_place<<<NCB, 256, 0, stream>>>(erow, ecol, ew, ghist, bdata);
  k_bsort<<<NBUCK, 256, 0, stream>>>(bcnt, bbase, bdata, cw, rp);

  // weights (BN folded, transposed, bf16)
  k_prep<<<256, 256, 0, stream>>>(W1, b1, g1, be1, m1, v1, W1t, bp1, 256);
  k_prep<<<256, 256, 0, stream>>>(W2, b2, g2, be2, m2, v2, W2t, bp2, 256);
  k_prep<<<128, 256, 0, stream>>>(W3, b3, nullptr, nullptr, nullptr, nullptr, W3t, bp3, 64);

  // x -> bf16
  k_f2bf8<<<(NN * 256) / (256 * 8), 256, 0, stream>>>(x, bufA);

  const int gm = (NN + 127) / 128;
  // layer 1: z1 = x @ W1' + b1'
  k_gemm<<<dim3(gm, 2), 256, 0, stream>>>(bufA, W1t, bp1, bufB, NN, 256, 256);
  // h1 = relu(P @ z1)
  k_spmm256<<<NN / 4, 256, 0, stream>>>(rp, cw, bufB, bufA);
  // layer 2: z2 = h1 @ W2' + b2'
  k_gemm<<<dim3(gm, 2), 256, 0, stream>>>(bufA, W2t, bp2, bufB, NN, 256, 256);
  // h2 = relu(P @ z2)
  k_spmm256<<<NN / 4, 256, 0, stream>>>(rp, cw, bufB, bufA);
  // layer 3: z3 = h2 @ W3 + b3
  k_gemm<<<dim3(gm, 1), 256, 0, stream>>>(bufA, W3t, bp3, bufC, NN, 64, 64);
  // out = log_softmax(P @ z3)
  k_spmm64<<<NN / 4, 256, 0, stream>>>(rp, cw, bufC, (float*)d_out);
}

// Round 8
// 545.695 us; speedup vs baseline: 1.5214x; 1.3851x over previous
//
#include <hip/hip_runtime.h>

#define NN 100000
#define NE 3200000
#define NBUCK 782   // ceil(NN/128)
#define EPB 8192
#define NCB 391     // ceil(NE/EPB)

typedef __attribute__((ext_vector_type(8))) short bf16x8;
typedef __attribute__((ext_vector_type(4))) float f32x4;
typedef __attribute__((ext_vector_type(2))) float f32x2;

__device__ __forceinline__ ushort f2bf(float f) {
  unsigned u = __builtin_bit_cast(unsigned, f);
  u = (u + 0x7FFFu + ((u >> 16) & 1u)) >> 16;
  return (ushort)u;
}
__device__ __forceinline__ float bf2f(ushort h) {
  return __builtin_bit_cast(float, ((unsigned)h) << 16);
}
// f32 -> fp8 e4m3 (OCP), single byte
__device__ __forceinline__ unsigned char f2fp8(float f) {
  return (unsigned char)(__builtin_amdgcn_cvt_pk_fp8_f32(f, 0.f, 0u, false) & 0xFFu);
}
__device__ __forceinline__ void gl2lds16(const void* g, void* s) {
  __builtin_amdgcn_global_load_lds((const __attribute__((address_space(1))) void*)g,
                                   (__attribute__((address_space(3))) void*)s, 16, 0, 0);
}

// ---------------- CSR build: two-pass block-local counting sort ----------------
__global__ __launch_bounds__(256) void k_cnt(const int* __restrict__ row, int* __restrict__ ghist,
                                             int* __restrict__ bcnt) {
  __shared__ int h[NBUCK];
  int blk = blockIdx.x, tid = threadIdx.x;
  for (int i = tid; i < NBUCK; i += 256) h[i] = 0;
  __syncthreads();
  int lo = blk * EPB, hi = lo + EPB; if (hi > NE) hi = NE;
  for (int i = lo + tid * 4; i < hi; i += 1024) {
    int4 r = *(const int4*)(row + i);
    atomicAdd(&h[r.x >> 7], 1);
    atomicAdd(&h[r.y >> 7], 1);
    atomicAdd(&h[r.z >> 7], 1);
    atomicAdd(&h[r.w >> 7], 1);
  }
  __syncthreads();
  for (int i = tid; i < NBUCK; i += 256) {
    ghist[(size_t)i * NCB + blk] = h[i];
    if (h[i]) atomicAdd(&bcnt[i], h[i]);
  }
}

__global__ __launch_bounds__(1024) void k_bscan(const int* __restrict__ bcnt, int* __restrict__ bbase) {
  __shared__ int s[1024];
  int t = threadIdx.x;
  s[t] = (t < NBUCK) ? bcnt[t] : 0;
  __syncthreads();
  for (int o = 1; o < 1024; o <<= 1) {
    int v = (t >= o) ? s[t - o] : 0;
    __syncthreads();
    s[t] += v;
    __syncthreads();
  }
  if (t < NBUCK) bbase[t] = t ? s[t - 1] : 0;
}

__global__ __launch_bounds__(64) void k_scan3(int* __restrict__ ghist, const int* __restrict__ bbase) {
  int b = blockIdx.x, lane = threadIdx.x;
  int carry = bbase[b];
#pragma unroll
  for (int r = 0; r < 7; ++r) {
    int idx = r * 64 + lane;
    int v = (idx < NCB) ? ghist[(size_t)b * NCB + idx] : 0;
    int s = v;
#pragma unroll
    for (int o = 1; o < 64; o <<= 1) { int t = __shfl_up(s, o, 64); if (lane >= o) s += t; }
    if (idx < NCB) ghist[(size_t)b * NCB + idx] = carry + s - v;
    carry += __shfl(s, 63, 64);
  }
}

__global__ __launch_bounds__(256) void k_place(const int* __restrict__ row, const int* __restrict__ col,
                                               const float* __restrict__ w, const int* __restrict__ ghist,
                                               int2* __restrict__ bdata) {
  __shared__ int offs[NBUCK];
  int blk = blockIdx.x, tid = threadIdx.x;
  for (int i = tid; i < NBUCK; i += 256) offs[i] = ghist[(size_t)i * NCB + blk];
  __syncthreads();
  int lo = blk * EPB, hi = lo + EPB; if (hi > NE) hi = NE;
  for (int i = lo + tid * 4; i < hi; i += 1024) {
    int4 r = *(const int4*)(row + i);
    int4 c = *(const int4*)(col + i);
    float4 ww = *(const float4*)(w + i);
    int p;
    p = atomicAdd(&offs[r.x >> 7], 1); bdata[p] = make_int2(((r.x & 127) << 17) | c.x, __float_as_int(ww.x));
    p = atomicAdd(&offs[r.y >> 7], 1); bdata[p] = make_int2(((r.y & 127) << 17) | c.y, __float_as_int(ww.y));
    p = atomicAdd(&offs[r.z >> 7], 1); bdata[p] = make_int2(((r.z & 127) << 17) | c.z, __float_as_int(ww.z));
    p = atomicAdd(&offs[r.w >> 7], 1); bdata[p] = make_int2(((r.w & 127) << 17) | c.w, __float_as_int(ww.w));
  }
}

__global__ __launch_bounds__(256) void k_bsort(const int* __restrict__ bcnt, const int* __restrict__ bbase,
                                               const int2* __restrict__ bdata, int2* __restrict__ cw,
                                               int* __restrict__ rp) {
  __shared__ int sc[128], lpos[128];
  int b = blockIdx.x, t = threadIdx.x;
  int n = bcnt[b], base = bbase[b];
  if (t < 128) sc[t] = 0;
  __syncthreads();
  for (int i = t; i < n; i += 256) {
    int r = bdata[(size_t)base + i].x >> 17;
    atomicAdd(&sc[r], 1);
  }
  __syncthreads();
  for (int o = 1; o < 128; o <<= 1) {
    int v = (t < 128 && t >= o) ? sc[t - o] : 0;
    __syncthreads();
    if (t < 128) sc[t] += v;
    __syncthreads();
  }
  if (t < 128) {
    int excl = t ? sc[t - 1] : 0;
    lpos[t] = excl;
    int grow = b * 128 + t;
    if (grow <= NN) rp[grow] = base + excl;
  }
  __syncthreads();
  for (int i = t; i < n; i += 256) {
    int2 e = bdata[(size_t)base + i];
    int r = e.x >> 17;
    int p = atomicAdd(&lpos[r], 1);
    cw[base + p] = make_int2(e.x & 0x1FFFF, e.y);
  }
}

// ---------------- weight prep: fold BN, transpose to [N][K], cast bf16 ----------------
__global__ __launch_bounds__(256) void k_prep(const float* __restrict__ W, const float* __restrict__ b,
                                              const float* __restrict__ g, const float* __restrict__ be,
                                              const float* __restrict__ m, const float* __restrict__ v,
                                              ushort* __restrict__ Wt, float* __restrict__ bp, int Ncol) {
  int j = blockIdx.x, k = threadIdx.x;
  float val = 0.f;
  if (j < Ncol) {
    float s = 1.f, t = 0.f;
    if (g) { s = g[j] * rsqrtf(v[j] + 1e-5f); t = be[j] - m[j] * s; }
    val = W[(size_t)k * Ncol + j] * s;
    if (k == 0) bp[j] = b[j] * s + t;
  } else if (k == 0) bp[j] = 0.f;
  Wt[(size_t)j * 256 + k] = f2bf(val);
}

// ---------------- x fp32 -> bf16 ----------------
__global__ __launch_bounds__(256) void k_f2bf8(const float* __restrict__ x, ushort* __restrict__ o) {
  size_t i = ((size_t)blockIdx.x * 256 + threadIdx.x) * 8;
  float4 u = *(const float4*)(x + i);
  float4 v = *(const float4*)(x + i + 4);
  ushort4 r0; r0.x = f2bf(u.x); r0.y = f2bf(u.y); r0.z = f2bf(u.z); r0.w = f2bf(u.w);
  ushort4 r1; r1.x = f2bf(v.x); r1.y = f2bf(v.y); r1.z = f2bf(v.z); r1.w = f2bf(v.w);
  *(ushort4*)(o + i) = r0;
  *(ushort4*)(o + i + 4) = r1;
}

// ---------------- bf16 MFMA GEMM: C[M x ncst] = A[M x 256] @ Wt^T + bias, fp8 out ----------------
__global__ __launch_bounds__(256) void k_gemm(const ushort* __restrict__ A, const ushort* __restrict__ Bt,
                                              const float* __restrict__ bp, unsigned char* __restrict__ C,
                                              int M, int ldc, int ncst) {
  __shared__ ushort sA[128 * 64];
  __shared__ ushort sB[128 * 64];
  const int tid = threadIdx.x;
  const int lane = tid & 63;
  const int wave = tid >> 6;
  const int wm = wave >> 1, wn = wave & 1;
  const int bm = blockIdx.x, bn = blockIdx.y;

  f32x4 acc[4][4];
#pragma unroll
  for (int a = 0; a < 4; ++a)
#pragma unroll
    for (int b = 0; b < 4; ++b) acc[a][b] = (f32x4){0.f, 0.f, 0.f, 0.f};

  const char* Ab = (const char*)A;
  const char* Bb = (const char*)Bt;
  char* sAb = (char*)sA;
  char* sBb = (char*)sB;

  for (int kt = 0; kt < 4; ++kt) {
#pragma unroll
    for (int it = 0; it < 4; ++it) {
      int o = tid * 16 + it * 4096;
      int r = o >> 7, kb = o & 127;
      int ra = bm * 128 + r; if (ra >= M) ra = M - 1;
      gl2lds16(Ab + (size_t)ra * 512 + kt * 128 + kb, sAb + o);
      gl2lds16(Bb + (size_t)(bn * 128 + r) * 512 + kt * 128 + kb, sBb + o);
    }
    __syncthreads();
#pragma unroll
    for (int kk = 0; kk < 2; ++kk) {
      int kByte = kk * 64 + ((lane >> 4) << 4);
      bf16x8 af[4], bfr[4];
#pragma unroll
      for (int mi = 0; mi < 4; ++mi)
        af[mi] = *(const bf16x8*)(sAb + (wm * 64 + mi * 16 + (lane & 15)) * 128 + kByte);
#pragma unroll
      for (int ni = 0; ni < 4; ++ni)
        bfr[ni] = *(const bf16x8*)(sBb + (wn * 64 + ni * 16 + (lane & 15)) * 128 + kByte);
#pragma unroll
      for (int mi = 0; mi < 4; ++mi)
#pragma unroll
        for (int ni = 0; ni < 4; ++ni)
          acc[mi][ni] = __builtin_amdgcn_mfma_f32_16x16x32_bf16(af[mi], bfr[ni], acc[mi][ni], 0, 0, 0);
    }
    __syncthreads();
  }

  const int r0 = bm * 128 + wm * 64 + ((lane >> 4) << 2);
  const int c0 = bn * 128 + wn * 64 + (lane & 15);
#pragma unroll
  for (int ni = 0; ni < 4; ++ni) {
    int col = c0 + ni * 16;
    if (col >= ncst) continue;
    float bpv = bp[col];
#pragma unroll
    for (int mi = 0; mi < 4; ++mi)
#pragma unroll
      for (int i = 0; i < 4; ++i) {
        int row = r0 + mi * 16 + i;
        if (row < M) C[(size_t)row * ldc + col] = f2fp8(acc[mi][ni][i] + bpv);
      }
  }
}

// gather-accumulate one batch of up to 16 edges (fp8 source, 4 dims/lane)
__device__ __forceinline__ void gacc16(const int2* __restrict__ cw, int i, int rem,
                                       const char* __restrict__ Hb, f32x2& a01, f32x2& a23) {
  int2 p[16]; unsigned g[16];
#pragma unroll
  for (int u = 0; u < 16; ++u) p[u] = cw[i + (u < rem ? u : 0)];
#pragma unroll
  for (int u = 0; u < 16; ++u) g[u] = *(const unsigned*)(Hb + ((size_t)(unsigned)p[u].x << 8));
#pragma unroll
  for (int u = 0; u < 16; ++u) {
    float wf = (u < rem) ? __int_as_float(p[u].y) : 0.f;
    f32x2 wv = {wf, wf};
    a01 += wv * __builtin_amdgcn_cvt_pk_f32_fp8(g[u], false);
    a23 += wv * __builtin_amdgcn_cvt_pk_f32_fp8(g[u], true);
  }
}

// ---------------- SpMM 256-dim: Y[i,:] = relu(sum w_e * H[col_e,:]), fp8 in, bf16 out ----------------
__global__ __launch_bounds__(256) void k_spmm256(const int* __restrict__ rp, const int2* __restrict__ cw,
                                                 const unsigned char* __restrict__ H, ushort* __restrict__ Y) {
  int node = blockIdx.x * 4 + (threadIdx.x >> 6);
  int lane = threadIdx.x & 63;
  int s = __builtin_amdgcn_readfirstlane(rp[node]);
  int e = __builtin_amdgcn_readfirstlane(rp[node + 1]);
  f32x2 a01 = {0.f, 0.f}, a23 = {0.f, 0.f};
  const char* Hb = (const char*)H + (lane << 2);   // 4 fp8 dims per lane
  int i = s;
  for (; i + 16 <= e; i += 16) gacc16(cw, i, 16, Hb, a01, a23);
  int rem = e - i;
  if (rem) gacc16(cw, i, rem, Hb, a01, a23);
  ushort4 o;
  o.x = f2bf(fmaxf(a01.x, 0.f)); o.y = f2bf(fmaxf(a01.y, 0.f));
  o.z = f2bf(fmaxf(a23.x, 0.f)); o.w = f2bf(fmaxf(a23.y, 0.f));
  *(ushort4*)(Y + (size_t)node * 256 + (lane << 2)) = o;
}

// ---------------- SpMM 64-dim + fused log_softmax, fp8 in, fp32 out ----------------
__device__ __forceinline__ void gacc64(const int2* __restrict__ cw, int i, int rem,
                                       const unsigned char* __restrict__ H, int word, int shift, float& a) {
  int2 p[16]; unsigned g[16];
#pragma unroll
  for (int u = 0; u < 16; ++u) p[u] = cw[i + (u < rem ? u : 0)];
#pragma unroll
  for (int u = 0; u < 16; ++u)
    g[u] = *(const unsigned*)(H + ((size_t)(unsigned)p[u].x << 6) + word);
#pragma unroll
  for (int u = 0; u < 16; ++u) {
    float h = __builtin_amdgcn_cvt_f32_fp8(g[u] >> shift, 0);
    a += ((u < rem) ? __int_as_float(p[u].y) : 0.f) * h;
  }
}

__global__ __launch_bounds__(256) void k_spmm64(const int* __restrict__ rp, const int2* __restrict__ cw,
                                                const unsigned char* __restrict__ H, float* __restrict__ out) {
  int node = blockIdx.x * 4 + (threadIdx.x >> 6);
  int lane = threadIdx.x & 63;
  int s = __builtin_amdgcn_readfirstlane(rp[node]);
  int e = __builtin_amdgcn_readfirstlane(rp[node + 1]);
  int word = (lane >> 2) << 2;      // dword offset within 64B row
  int shift = (lane & 3) << 3;      // byte within dword
  float a = 0.f;
  int i = s;
  for (; i + 16 <= e; i += 16) gacc64(cw, i, 16, H, word, shift, a);
  int rem = e - i;
  if (rem) gacc64(cw, i, rem, H, word, shift, a);
  float mx = a;
#pragma unroll
  for (int o = 32; o > 0; o >>= 1) mx = fmaxf(mx, __shfl_xor(mx, o, 64));
  float ex = expf(a - mx);
  float sum = ex;
#pragma unroll
  for (int o = 32; o > 0; o >>= 1) sum += __shfl_xor(sum, o, 64);
  out[(size_t)node * 64 + lane] = (a - mx) - logf(sum);
}

extern "C" void kernel_launch(void* const* d_in, const int* in_sizes, int n_in,
                              void* d_out, int out_size, void* d_ws, size_t ws_size,
                              hipStream_t stream) {
  const float* x   = (const float*)d_in[0];
  const int* erow  = (const int*)d_in[1];
  const int* ecol  = (const int*)d_in[2];
  const float* ew  = (const float*)d_in[3];
  const float* W1  = (const float*)d_in[4];
  const float* b1  = (const float*)d_in[5];
  const float* g1  = (const float*)d_in[6];
  const float* be1 = (const float*)d_in[7];
  const float* m1  = (const float*)d_in[8];
  const float* v1  = (const float*)d_in[9];
  const float* W2  = (const float*)d_in[10];
  const float* b2  = (const float*)d_in[11];
  const float* g2  = (const float*)d_in[12];
  const float* be2 = (const float*)d_in[13];
  const float* m2  = (const float*)d_in[14];
  const float* v2  = (const float*)d_in[15];
  const float* W3  = (const float*)d_in[16];
  const float* b3  = (const float*)d_in[17];

  char* ws = (char*)d_ws;
  size_t off = 0;
  auto carve = [&](size_t bytes) -> void* {
    void* p = ws + off;
    off += (bytes + 511) & ~(size_t)511;
    return p;
  };
  int* bcnt   = (int*)carve((size_t)NBUCK * 4);
  int* bbase  = (int*)carve((size_t)NBUCK * 4);
  int* ghist  = (int*)carve((size_t)NBUCK * NCB * 4);
  int* rp     = (int*)carve((size_t)(NBUCK * 128 + 1) * 4);
  int2* cw    = (int2*)carve((size_t)NE * 8);
  ushort* W1t = (ushort*)carve(256 * 256 * 2);
  ushort* W2t = (ushort*)carve(256 * 256 * 2);
  ushort* W3t = (ushort*)carve(128 * 256 * 2);
  float* bp1  = (float*)carve(256 * 4);
  float* bp2  = (float*)carve(256 * 4);
  float* bp3  = (float*)carve(128 * 4);
  ushort* bufH        = (ushort*)carve((size_t)NN * 256 * 2);        // bf16: x, h1, h2
  unsigned char* bufZ = (unsigned char*)carve((size_t)NN * 256);     // fp8: z1, z2
  unsigned char* bufZ3 = (unsigned char*)carve((size_t)NN * 64);     // fp8: z3
  if (off > ws_size) return;

  // bucket scratch aliases bufH (not live until k_f2bf8): NE*8 = 25.6MB <= 51.2MB
  int2* bdata = (int2*)bufH;

  // CSR build (two-pass block-local counting sort, no contended global atomics)
  hipMemsetAsync(bcnt, 0, (size_t)NBUCK * 4, stream);
  k_cnt<<<NCB, 256, 0, stream>>>(erow, ghist, bcnt);
  k_bscan<<<1, 1024, 0, stream>>>(bcnt, bbase);
  k_scan3<<<NBUCK, 64, 0, stream>>>(ghist, bbase);
  k_place<<<NCB, 256, 0, stream>>>(erow, ecol, ew, ghist, bdata);
  k_bsort<<<NBUCK, 256, 0, stream>>>(bcnt, bbase, bdata, cw, rp);

  // weights (BN folded, transposed, bf16)
  k_prep<<<256, 256, 0, stream>>>(W1, b1, g1, be1, m1, v1, W1t, bp1, 256);
  k_prep<<<256, 256, 0, stream>>>(W2, b2, g2, be2, m2, v2, W2t, bp2, 256);
  k_prep<<<128, 256, 0, stream>>>(W3, b3, nullptr, nullptr, nullptr, nullptr, W3t, bp3, 64);

  // x -> bf16
  k_f2bf8<<<(NN * 256) / (256 * 8), 256, 0, stream>>>(x, bufH);

  const int gm = (NN + 127) / 128;
  // layer 1: z1 = x @ W1' + b1'           (fp8 out)
  k_gemm<<<dim3(gm, 2), 256, 0, stream>>>(bufH, W1t, bp1, bufZ, NN, 256, 256);
  // h1 = relu(P @ z1)                     (bf16 out, overwrites x)
  k_spmm256<<<NN / 4, 256, 0, stream>>>(rp, cw, bufZ, bufH);
  // layer 2: z2 = h1 @ W2' + b2'          (fp8 out)
  k_gemm<<<dim3(gm, 2), 256, 0, stream>>>(bufH, W2t, bp2, bufZ, NN, 256, 256);
  // h2 = relu(P @ z2)
  k_spmm256<<<NN / 4, 256, 0, stream>>>(rp, cw, bufZ, bufH);
  // layer 3: z3 = h2 @ W3 + b3            (fp8 out)
  k_gemm<<<dim3(gm, 1), 256, 0, stream>>>(bufH, W3t, bp3, bufZ3, NN, 64, 64);
  // out = log_softmax(P @ z3)
  k_spmm64<<<NN / 4, 256, 0, stream>>>(rp, cw, bufZ3, (float*)d_out);
}

// Round 9
// 519.125 us; speedup vs baseline: 1.5992x; 1.0512x over previous
//
#include <hip/hip_runtime.h>

#define NN 100000
#define NE 3200000
#define NBUCK 782   // ceil(NN/128)
#define EPB 8192
#define NCB 391     // ceil(NE/EPB)

typedef __attribute__((ext_vector_type(8))) short bf16x8;
typedef __attribute__((ext_vector_type(4))) float f32x4;
typedef __attribute__((ext_vector_type(2))) float f32x2;

__device__ __forceinline__ ushort f2bf(float f) {
  unsigned u = __builtin_bit_cast(unsigned, f);
  u = (u + 0x7FFFu + ((u >> 16) & 1u)) >> 16;
  return (ushort)u;
}
__device__ __forceinline__ float bf2f(ushort h) {
  return __builtin_bit_cast(float, ((unsigned)h) << 16);
}
// f32 -> fp8 e4m3 (OCP), single byte
__device__ __forceinline__ unsigned char f2fp8(float f) {
  return (unsigned char)(__builtin_amdgcn_cvt_pk_fp8_f32(f, 0.f, 0u, false) & 0xFFu);
}
// packed edge: [31:15]=col (17b), [14:0]=bf16(w) sans sign (w >= 0)
__device__ __forceinline__ float pw2w(unsigned pw) {
  return __builtin_bit_cast(float, (pw & 0x7FFFu) << 16);
}
__device__ __forceinline__ void gl2lds16(const void* g, void* s) {
  __builtin_amdgcn_global_load_lds((const __attribute__((address_space(1))) void*)g,
                                   (__attribute__((address_space(3))) void*)s, 16, 0, 0);
}

// ---------------- CSR build: two-pass block-local counting sort ----------------
__global__ __launch_bounds__(256) void k_cnt(const int* __restrict__ row, int* __restrict__ ghist,
                                             int* __restrict__ bcnt) {
  __shared__ int h[NBUCK];
  int blk = blockIdx.x, tid = threadIdx.x;
  for (int i = tid; i < NBUCK; i += 256) h[i] = 0;
  __syncthreads();
  int lo = blk * EPB, hi = lo + EPB; if (hi > NE) hi = NE;
  for (int i = lo + tid * 4; i < hi; i += 1024) {
    int4 r = *(const int4*)(row + i);
    atomicAdd(&h[r.x >> 7], 1);
    atomicAdd(&h[r.y >> 7], 1);
    atomicAdd(&h[r.z >> 7], 1);
    atomicAdd(&h[r.w >> 7], 1);
  }
  __syncthreads();
  for (int i = tid; i < NBUCK; i += 256) {
    ghist[(size_t)i * NCB + blk] = h[i];
    if (h[i]) atomicAdd(&bcnt[i], h[i]);
  }
}

__global__ __launch_bounds__(1024) void k_bscan(const int* __restrict__ bcnt, int* __restrict__ bbase) {
  __shared__ int s[1024];
  int t = threadIdx.x;
  s[t] = (t < NBUCK) ? bcnt[t] : 0;
  __syncthreads();
  for (int o = 1; o < 1024; o <<= 1) {
    int v = (t >= o) ? s[t - o] : 0;
    __syncthreads();
    s[t] += v;
    __syncthreads();
  }
  if (t < NBUCK) bbase[t] = t ? s[t - 1] : 0;
}

__global__ __launch_bounds__(64) void k_scan3(int* __restrict__ ghist, const int* __restrict__ bbase) {
  int b = blockIdx.x, lane = threadIdx.x;
  int carry = bbase[b];
#pragma unroll
  for (int r = 0; r < 7; ++r) {
    int idx = r * 64 + lane;
    int v = (idx < NCB) ? ghist[(size_t)b * NCB + idx] : 0;
    int s = v;
#pragma unroll
    for (int o = 1; o < 64; o <<= 1) { int t = __shfl_up(s, o, 64); if (lane >= o) s += t; }
    if (idx < NCB) ghist[(size_t)b * NCB + idx] = carry + s - v;
    carry += __shfl(s, 63, 64);
  }
}

__global__ __launch_bounds__(256) void k_place(const int* __restrict__ row, const int* __restrict__ col,
                                               const float* __restrict__ w, const int* __restrict__ ghist,
                                               int2* __restrict__ bdata) {
  __shared__ int offs[NBUCK];
  int blk = blockIdx.x, tid = threadIdx.x;
  for (int i = tid; i < NBUCK; i += 256) offs[i] = ghist[(size_t)i * NCB + blk];
  __syncthreads();
  int lo = blk * EPB, hi = lo + EPB; if (hi > NE) hi = NE;
  for (int i = lo + tid * 4; i < hi; i += 1024) {
    int4 r = *(const int4*)(row + i);
    int4 c = *(const int4*)(col + i);
    float4 ww = *(const float4*)(w + i);
    int p;
    p = atomicAdd(&offs[r.x >> 7], 1); bdata[p] = make_int2(((r.x & 127) << 17) | c.x, __float_as_int(ww.x));
    p = atomicAdd(&offs[r.y >> 7], 1); bdata[p] = make_int2(((r.y & 127) << 17) | c.y, __float_as_int(ww.y));
    p = atomicAdd(&offs[r.z >> 7], 1); bdata[p] = make_int2(((r.z & 127) << 17) | c.z, __float_as_int(ww.z));
    p = atomicAdd(&offs[r.w >> 7], 1); bdata[p] = make_int2(((r.w & 127) << 17) | c.w, __float_as_int(ww.w));
  }
}

__global__ __launch_bounds__(256) void k_bsort(const int* __restrict__ bcnt, const int* __restrict__ bbase,
                                               const int2* __restrict__ bdata, unsigned* __restrict__ cw,
                                               int* __restrict__ rp) {
  __shared__ int sc[128], lpos[128];
  int b = blockIdx.x, t = threadIdx.x;
  int n = bcnt[b], base = bbase[b];
  if (t < 128) sc[t] = 0;
  __syncthreads();
  for (int i = t; i < n; i += 256) {
    int r = bdata[(size_t)base + i].x >> 17;
    atomicAdd(&sc[r], 1);
  }
  __syncthreads();
  for (int o = 1; o < 128; o <<= 1) {
    int v = (t < 128 && t >= o) ? sc[t - o] : 0;
    __syncthreads();
    if (t < 128) sc[t] += v;
    __syncthreads();
  }
  if (t < 128) {
    int excl = t ? sc[t - 1] : 0;
    lpos[t] = excl;
    int grow = b * 128 + t;
    if (grow <= NN) rp[grow] = base + excl;
  }
  __syncthreads();
  for (int i = t; i < n; i += 256) {
    int2 e = bdata[(size_t)base + i];
    int r = e.x >> 17;
    int p = atomicAdd(&lpos[r], 1);
    cw[base + p] = ((unsigned)(e.x & 0x1FFFF) << 15) | (f2bf(__int_as_float(e.y)) & 0x7FFFu);
  }
}

// ---------------- fused weight prep (BN fold, transpose, bf16, W3 zero-pad) + bcnt zero ----------------
__global__ __launch_bounds__(256) void k_prepall(
    const float* __restrict__ W1, const float* __restrict__ b1, const float* __restrict__ g1,
    const float* __restrict__ be1, const float* __restrict__ m1, const float* __restrict__ v1,
    const float* __restrict__ W2, const float* __restrict__ b2, const float* __restrict__ g2,
    const float* __restrict__ be2, const float* __restrict__ m2, const float* __restrict__ v2,
    const float* __restrict__ W3, const float* __restrict__ b3,
    ushort* __restrict__ W1t, ushort* __restrict__ W2t, ushort* __restrict__ W3t,
    float* __restrict__ bp1, float* __restrict__ bp2, float* __restrict__ bp3,
    int* __restrict__ bcnt) {
  int blk = blockIdx.x, k = threadIdx.x;
  if (blk < 4) { int z = blk * 256 + k; if (z < NBUCK) bcnt[z] = 0; }
  if (blk < 256) {
    int j = blk;
    float s = g1[j] * rsqrtf(v1[j] + 1e-5f), t = be1[j] - m1[j] * s;
    if (k == 0) bp1[j] = b1[j] * s + t;
    W1t[(size_t)j * 256 + k] = f2bf(W1[(size_t)k * 256 + j] * s);
  } else if (blk < 512) {
    int j = blk - 256;
    float s = g2[j] * rsqrtf(v2[j] + 1e-5f), t = be2[j] - m2[j] * s;
    if (k == 0) bp2[j] = b2[j] * s + t;
    W2t[(size_t)j * 256 + k] = f2bf(W2[(size_t)k * 256 + j] * s);
  } else {
    int j = blk - 512;  // 0..127, rows >= 64 zero-padded
    if (k == 0) bp3[j] = (j < 64) ? b3[j] : 0.f;
    W3t[(size_t)j * 256 + k] = f2bf((j < 64) ? W3[(size_t)k * 64 + j] : 0.f);
  }
}

// ---------------- GEMM1: C = x[fp32] @ W1t^T + bias, fp8 out (fp32->bf16 reg-staged A) ----------------
__global__ __launch_bounds__(256) void k_gemm1(const float* __restrict__ A, const ushort* __restrict__ Bt,
                                               const float* __restrict__ bp, unsigned char* __restrict__ C,
                                               int M) {
  __shared__ ushort sA[128 * 64];
  __shared__ ushort sB[128 * 64];
  const int tid = threadIdx.x;
  const int lane = tid & 63;
  const int wave = tid >> 6;
  const int wm = wave >> 1, wn = wave & 1;
  const int bm = blockIdx.x, bn = blockIdx.y;

  f32x4 acc[4][4];
#pragma unroll
  for (int a = 0; a < 4; ++a)
#pragma unroll
    for (int b = 0; b < 4; ++b) acc[a][b] = (f32x4){0.f, 0.f, 0.f, 0.f};

  const char* Bb = (const char*)Bt;
  char* sAb = (char*)sA;
  char* sBb = (char*)sB;

  for (int kt = 0; kt < 4; ++kt) {
    // A: load fp32, convert, LDS write (16KB/kt)
#pragma unroll
    for (int it = 0; it < 4; ++it) {
      int idx = it * 2048 + tid * 8;
      int row = idx >> 6, colx = idx & 63;
      int ra = bm * 128 + row; if (ra >= M) ra = M - 1;
      const float* src = A + (size_t)ra * 256 + kt * 64 + colx;
      float4 u = *(const float4*)src;
      float4 v = *(const float4*)(src + 4);
      ushort4 r0; r0.x = f2bf(u.x); r0.y = f2bf(u.y); r0.z = f2bf(u.z); r0.w = f2bf(u.w);
      ushort4 r1; r1.x = f2bf(v.x); r1.y = f2bf(v.y); r1.z = f2bf(v.z); r1.w = f2bf(v.w);
      *(ushort4*)(sAb + row * 128 + colx * 2) = r0;
      *(ushort4*)(sAb + row * 128 + colx * 2 + 8) = r1;
    }
    // B: direct global->LDS
#pragma unroll
    for (int it = 0; it < 4; ++it) {
      int o = tid * 16 + it * 4096;
      int r = o >> 7, kb = o & 127;
      gl2lds16(Bb + (size_t)(bn * 128 + r) * 512 + kt * 128 + kb, sBb + o);
    }
    __syncthreads();
#pragma unroll
    for (int kk = 0; kk < 2; ++kk) {
      int kByte = kk * 64 + ((lane >> 4) << 4);
      bf16x8 af[4], bfr[4];
#pragma unroll
      for (int mi = 0; mi < 4; ++mi)
        af[mi] = *(const bf16x8*)(sAb + (wm * 64 + mi * 16 + (lane & 15)) * 128 + kByte);
#pragma unroll
      for (int ni = 0; ni < 4; ++ni)
        bfr[ni] = *(const bf16x8*)(sBb + (wn * 64 + ni * 16 + (lane & 15)) * 128 + kByte);
#pragma unroll
      for (int mi = 0; mi < 4; ++mi)
#pragma unroll
        for (int ni = 0; ni < 4; ++ni)
          acc[mi][ni] = __builtin_amdgcn_mfma_f32_16x16x32_bf16(af[mi], bfr[ni], acc[mi][ni], 0, 0, 0);
    }
    __syncthreads();
  }

  const int r0 = bm * 128 + wm * 64 + ((lane >> 4) << 2);
  const int c0 = bn * 128 + wn * 64 + (lane & 15);
#pragma unroll
  for (int ni = 0; ni < 4; ++ni) {
    int col = c0 + ni * 16;
    float bpv = bp[col];
#pragma unroll
    for (int mi = 0; mi < 4; ++mi)
#pragma unroll
      for (int i = 0; i < 4; ++i) {
        int row = r0 + mi * 16 + i;
        if (row < M) C[(size_t)row * 256 + col] = f2fp8(acc[mi][ni][i] + bpv);
      }
  }
}

// ---------------- bf16 MFMA GEMM: C[M x ncst] = A[M x 256] @ Wt^T + bias, fp8 out ----------------
__global__ __launch_bounds__(256) void k_gemm(const ushort* __restrict__ A, const ushort* __restrict__ Bt,
                                              const float* __restrict__ bp, unsigned char* __restrict__ C,
                                              int M, int ldc, int ncst) {
  __shared__ ushort sA[128 * 64];
  __shared__ ushort sB[128 * 64];
  const int tid = threadIdx.x;
  const int lane = tid & 63;
  const int wave = tid >> 6;
  const int wm = wave >> 1, wn = wave & 1;
  const int bm = blockIdx.x, bn = blockIdx.y;

  f32x4 acc[4][4];
#pragma unroll
  for (int a = 0; a < 4; ++a)
#pragma unroll
    for (int b = 0; b < 4; ++b) acc[a][b] = (f32x4){0.f, 0.f, 0.f, 0.f};

  const char* Ab = (const char*)A;
  const char* Bb = (const char*)Bt;
  char* sAb = (char*)sA;
  char* sBb = (char*)sB;

  for (int kt = 0; kt < 4; ++kt) {
#pragma unroll
    for (int it = 0; it < 4; ++it) {
      int o = tid * 16 + it * 4096;
      int r = o >> 7, kb = o & 127;
      int ra = bm * 128 + r; if (ra >= M) ra = M - 1;
      gl2lds16(Ab + (size_t)ra * 512 + kt * 128 + kb, sAb + o);
      gl2lds16(Bb + (size_t)(bn * 128 + r) * 512 + kt * 128 + kb, sBb + o);
    }
    __syncthreads();
#pragma unroll
    for (int kk = 0; kk < 2; ++kk) {
      int kByte = kk * 64 + ((lane >> 4) << 4);
      bf16x8 af[4], bfr[4];
#pragma unroll
      for (int mi = 0; mi < 4; ++mi)
        af[mi] = *(const bf16x8*)(sAb + (wm * 64 + mi * 16 + (lane & 15)) * 128 + kByte);
#pragma unroll
      for (int ni = 0; ni < 4; ++ni)
        bfr[ni] = *(const bf16x8*)(sBb + (wn * 64 + ni * 16 + (lane & 15)) * 128 + kByte);
#pragma unroll
      for (int mi = 0; mi < 4; ++mi)
#pragma unroll
        for (int ni = 0; ni < 4; ++ni)
          acc[mi][ni] = __builtin_amdgcn_mfma_f32_16x16x32_bf16(af[mi], bfr[ni], acc[mi][ni], 0, 0, 0);
    }
    __syncthreads();
  }

  const int r0 = bm * 128 + wm * 64 + ((lane >> 4) << 2);
  const int c0 = bn * 128 + wn * 64 + (lane & 15);
#pragma unroll
  for (int ni = 0; ni < 4; ++ni) {
    int col = c0 + ni * 16;
    if (col >= ncst) continue;
    float bpv = bp[col];
#pragma unroll
    for (int mi = 0; mi < 4; ++mi)
#pragma unroll
      for (int i = 0; i < 4; ++i) {
        int row = r0 + mi * 16 + i;
        if (row < M) C[(size_t)row * ldc + col] = f2fp8(acc[mi][ni][i] + bpv);
      }
  }
}

// gather-accumulate one batch of up to 16 edges (fp8 source, packed 4B cw)
__device__ __forceinline__ void gacc16(const unsigned* __restrict__ cw, int i, int rem,
                                       const char* __restrict__ Hb, f32x2& a01, f32x2& a23) {
  unsigned p[16]; unsigned g[16];
#pragma unroll
  for (int u = 0; u < 16; ++u) p[u] = cw[i + (u < rem ? u : 0)];
#pragma unroll
  for (int u = 0; u < 16; ++u) g[u] = *(const unsigned*)(Hb + ((size_t)(p[u] >> 15) << 8));
#pragma unroll
  for (int u = 0; u < 16; ++u) {
    float wf = (u < rem) ? pw2w(p[u]) : 0.f;
    f32x2 wv = {wf, wf};
    a01 += wv * __builtin_amdgcn_cvt_pk_f32_fp8(g[u], false);
    a23 += wv * __builtin_amdgcn_cvt_pk_f32_fp8(g[u], true);
  }
}

// ---------------- SpMM 256-dim: Y[i,:] = relu(sum w_e * H[col_e,:]), fp8 in, bf16 out ----------------
__global__ __launch_bounds__(256) void k_spmm256(const int* __restrict__ rp, const unsigned* __restrict__ cw,
                                                 const unsigned char* __restrict__ H, ushort* __restrict__ Y) {
  int node = blockIdx.x * 4 + (threadIdx.x >> 6);
  int lane = threadIdx.x & 63;
  int s = __builtin_amdgcn_readfirstlane(rp[node]);
  int e = __builtin_amdgcn_readfirstlane(rp[node + 1]);
  f32x2 a01 = {0.f, 0.f}, a23 = {0.f, 0.f};
  const char* Hb = (const char*)H + (lane << 2);   // 4 fp8 dims per lane
  int i = s;
  for (; i + 16 <= e; i += 16) gacc16(cw, i, 16, Hb, a01, a23);
  int rem = e - i;
  if (rem) gacc16(cw, i, rem, Hb, a01, a23);
  ushort4 o;
  o.x = f2bf(fmaxf(a01.x, 0.f)); o.y = f2bf(fmaxf(a01.y, 0.f));
  o.z = f2bf(fmaxf(a23.x, 0.f)); o.w = f2bf(fmaxf(a23.y, 0.f));
  *(ushort4*)(Y + (size_t)node * 256 + (lane << 2)) = o;
}

// ---------------- SpMM 64-dim + fused log_softmax, fp8 in, fp32 out ----------------
__device__ __forceinline__ void gacc64(const unsigned* __restrict__ cw, int i, int rem,
                                       const unsigned char* __restrict__ H, int word, int shift, float& a) {
  unsigned p[16]; unsigned g[16];
#pragma unroll
  for (int u = 0; u < 16; ++u) p[u] = cw[i + (u < rem ? u : 0)];
#pragma unroll
  for (int u = 0; u < 16; ++u)
    g[u] = *(const unsigned*)(H + ((size_t)(p[u] >> 15) << 6) + word);
#pragma unroll
  for (int u = 0; u < 16; ++u) {
    float h = __builtin_amdgcn_cvt_f32_fp8(g[u] >> shift, 0);
    a += ((u < rem) ? pw2w(p[u]) : 0.f) * h;
  }
}

__global__ __launch_bounds__(256) void k_spmm64(const int* __restrict__ rp, const unsigned* __restrict__ cw,
                                                const unsigned char* __restrict__ H, float* __restrict__ out) {
  int node = blockIdx.x * 4 + (threadIdx.x >> 6);
  int lane = threadIdx.x & 63;
  int s = __builtin_amdgcn_readfirstlane(rp[node]);
  int e = __builtin_amdgcn_readfirstlane(rp[node + 1]);
  int word = (lane >> 2) << 2;      // dword offset within 64B row
  int shift = (lane & 3) << 3;      // byte within dword
  float a = 0.f;
  int i = s;
  for (; i + 16 <= e; i += 16) gacc64(cw, i, 16, H, word, shift, a);
  int rem = e - i;
  if (rem) gacc64(cw, i, rem, H, word, shift, a);
  float mx = a;
#pragma unroll
  for (int o = 32; o > 0; o >>= 1) mx = fmaxf(mx, __shfl_xor(mx, o, 64));
  float ex = expf(a - mx);
  float sum = ex;
#pragma unroll
  for (int o = 32; o > 0; o >>= 1) sum += __shfl_xor(sum, o, 64);
  out[(size_t)node * 64 + lane] = (a - mx) - logf(sum);
}

extern "C" void kernel_launch(void* const* d_in, const int* in_sizes, int n_in,
                              void* d_out, int out_size, void* d_ws, size_t ws_size,
                              hipStream_t stream) {
  const float* x   = (const float*)d_in[0];
  const int* erow  = (const int*)d_in[1];
  const int* ecol  = (const int*)d_in[2];
  const float* ew  = (const float*)d_in[3];
  const float* W1  = (const float*)d_in[4];
  const float* b1  = (const float*)d_in[5];
  const float* g1  = (const float*)d_in[6];
  const float* be1 = (const float*)d_in[7];
  const float* m1  = (const float*)d_in[8];
  const float* v1  = (const float*)d_in[9];
  const float* W2  = (const float*)d_in[10];
  const float* b2  = (const float*)d_in[11];
  const float* g2  = (const float*)d_in[12];
  const float* be2 = (const float*)d_in[13];
  const float* m2  = (const float*)d_in[14];
  const float* v2  = (const float*)d_in[15];
  const float* W3  = (const float*)d_in[16];
  const float* b3  = (const float*)d_in[17];

  char* ws = (char*)d_ws;
  size_t off = 0;
  auto carve = [&](size_t bytes) -> void* {
    void* p = ws + off;
    off += (bytes + 511) & ~(size_t)511;
    return p;
  };
  int* bcnt    = (int*)carve((size_t)NBUCK * 4);
  int* bbase   = (int*)carve((size_t)NBUCK * 4);
  int* ghist   = (int*)carve((size_t)NBUCK * NCB * 4);
  int* rp      = (int*)carve((size_t)(NBUCK * 128 + 1) * 4);
  unsigned* cw = (unsigned*)carve((size_t)NE * 4);
  ushort* W1t  = (ushort*)carve(256 * 256 * 2);
  ushort* W2t  = (ushort*)carve(256 * 256 * 2);
  ushort* W3t  = (ushort*)carve(128 * 256 * 2);
  float* bp1   = (float*)carve(256 * 4);
  float* bp2   = (float*)carve(256 * 4);
  float* bp3   = (float*)carve(128 * 4);
  ushort* bufH        = (ushort*)carve((size_t)NN * 256 * 2);        // bf16: h1, h2 (+ CSR scratch)
  unsigned char* bufZ = (unsigned char*)carve((size_t)NN * 256);     // fp8: z1, z2
  unsigned char* bufZ3 = (unsigned char*)carve((size_t)NN * 64);     // fp8: z3
  if (off > ws_size) return;

  // bucket scratch aliases bufH (not live until spmm1 writes h1): NE*8 = 25.6MB <= 51.2MB
  int2* bdata = (int2*)bufH;

  // weight prep (also zeroes bcnt) then CSR build
  k_prepall<<<640, 256, 0, stream>>>(W1, b1, g1, be1, m1, v1, W2, b2, g2, be2, m2, v2,
                                     W3, b3, W1t, W2t, W3t, bp1, bp2, bp3, bcnt);
  k_cnt<<<NCB, 256, 0, stream>>>(erow, ghist, bcnt);
  k_bscan<<<1, 1024, 0, stream>>>(bcnt, bbase);
  k_scan3<<<NBUCK, 64, 0, stream>>>(ghist, bbase);
  k_place<<<NCB, 256, 0, stream>>>(erow, ecol, ew, ghist, bdata);
  k_bsort<<<NBUCK, 256, 0, stream>>>(bcnt, bbase, bdata, cw, rp);

  const int gm = (NN + 127) / 128;
  // layer 1: z1 = x @ W1' + b1'  (fp32 in, fp8 out)
  k_gemm1<<<dim3(gm, 2), 256, 0, stream>>>(x, W1t, bp1, bufZ, NN);
  // h1 = relu(P @ z1)
  k_spmm256<<<NN / 4, 256, 0, stream>>>(rp, cw, bufZ, bufH);
  // layer 2: z2 = h1 @ W2' + b2'
  k_gemm<<<dim3(gm, 2), 256, 0, stream>>>(bufH, W2t, bp2, bufZ, NN, 256, 256);
  // h2 = relu(P @ z2)
  k_spmm256<<<NN / 4, 256, 0, stream>>>(rp, cw, bufZ, bufH);
  // layer 3: z3 = h2 @ W3 + b3
  k_gemm<<<dim3(gm, 1), 256, 0, stream>>>(bufH, W3t, bp3, bufZ3, NN, 64, 64);
  // out = log_softmax(P @ z3)
  k_spmm64<<<NN / 4, 256, 0, stream>>>(rp, cw, bufZ3, (float*)d_out);
}

// Round 10
// 515.550 us; speedup vs baseline: 1.6103x; 1.0069x over previous
//
#include <hip/hip_runtime.h>

#define NN 100000
#define NE 3200000
#define NBUCK 782   // ceil(NN/128)
#define EPB 8192
#define NCB 391     // ceil(NE/EPB)

typedef __attribute__((ext_vector_type(8))) short bf16x8;
typedef __attribute__((ext_vector_type(4))) float f32x4;
typedef __attribute__((ext_vector_type(2))) float f32x2;

__device__ __forceinline__ ushort f2bf(float f) {
  unsigned u = __builtin_bit_cast(unsigned, f);
  u = (u + 0x7FFFu + ((u >> 16) & 1u)) >> 16;
  return (ushort)u;
}
__device__ __forceinline__ float bf2f(ushort h) {
  return __builtin_bit_cast(float, ((unsigned)h) << 16);
}
// f32 -> fp8 e4m3 (OCP), single byte
__device__ __forceinline__ unsigned char f2fp8(float f) {
  return (unsigned char)(__builtin_amdgcn_cvt_pk_fp8_f32(f, 0.f, 0u, false) & 0xFFu);
}
// packed edge: [31:15]=col (17b), [14:0]=bf16(w) sans sign (w >= 0)
__device__ __forceinline__ float pw2w(unsigned pw) {
  return __builtin_bit_cast(float, (pw & 0x7FFFu) << 16);
}
__device__ __forceinline__ void gl2lds16(const void* g, void* s) {
  __builtin_amdgcn_global_load_lds((const __attribute__((address_space(1))) void*)g,
                                   (__attribute__((address_space(3))) void*)s, 16, 0, 0);
}

// ---------------- merged: weight prep (blocks 0..639) | per-block histogram (blocks 640..1030) ----------------
__global__ __launch_bounds__(256) void k_pc(
    const float* __restrict__ W1, const float* __restrict__ b1, const float* __restrict__ g1,
    const float* __restrict__ be1, const float* __restrict__ m1, const float* __restrict__ v1,
    const float* __restrict__ W2, const float* __restrict__ b2, const float* __restrict__ g2,
    const float* __restrict__ be2, const float* __restrict__ m2, const float* __restrict__ v2,
    const float* __restrict__ W3, const float* __restrict__ b3,
    ushort* __restrict__ W1t, ushort* __restrict__ W2t, ushort* __restrict__ W3t,
    float* __restrict__ bp1, float* __restrict__ bp2, float* __restrict__ bp3,
    const int* __restrict__ row, int* __restrict__ ghist, int* __restrict__ bcnt) {
  __shared__ int h[NBUCK];
  int bid = blockIdx.x, k = threadIdx.x;
  if (bid < 640) {
    if (bid < 256) {
      int j = bid;
      float s = g1[j] * rsqrtf(v1[j] + 1e-5f), t = be1[j] - m1[j] * s;
      if (k == 0) bp1[j] = b1[j] * s + t;
      W1t[(size_t)j * 256 + k] = f2bf(W1[(size_t)k * 256 + j] * s);
    } else if (bid < 512) {
      int j = bid - 256;
      float s = g2[j] * rsqrtf(v2[j] + 1e-5f), t = be2[j] - m2[j] * s;
      if (k == 0) bp2[j] = b2[j] * s + t;
      W2t[(size_t)j * 256 + k] = f2bf(W2[(size_t)k * 256 + j] * s);
    } else {
      int j = bid - 512;  // 0..127, rows >= 64 zero-padded
      if (k == 0) bp3[j] = (j < 64) ? b3[j] : 0.f;
      W3t[(size_t)j * 256 + k] = f2bf((j < 64) ? W3[(size_t)k * 64 + j] : 0.f);
    }
    return;
  }
  int blk = bid - 640;
  for (int i = k; i < NBUCK; i += 256) h[i] = 0;
  __syncthreads();
  int lo = blk * EPB, hi = lo + EPB; if (hi > NE) hi = NE;
  for (int i = lo + k * 4; i < hi; i += 1024) {
    int4 r = *(const int4*)(row + i);
    atomicAdd(&h[r.x >> 7], 1);
    atomicAdd(&h[r.y >> 7], 1);
    atomicAdd(&h[r.z >> 7], 1);
    atomicAdd(&h[r.w >> 7], 1);
  }
  __syncthreads();
  for (int i = k; i < NBUCK; i += 256) {
    ghist[(size_t)i * NCB + blk] = h[i];
    if (h[i]) atomicAdd(&bcnt[i], h[i]);
  }
}

// ---------------- per-bucket scan (computes own base from bcnt; writes bbase) ----------------
__global__ __launch_bounds__(64) void k_scan3(int* __restrict__ ghist, const int* __restrict__ bcnt,
                                              int* __restrict__ bbase) {
  int b = blockIdx.x, lane = threadIdx.x;
  int acc = 0;
  for (int i = lane; i < b; i += 64) acc += bcnt[i];
#pragma unroll
  for (int o = 32; o > 0; o >>= 1) acc += __shfl_xor(acc, o, 64);
  int carry = acc;   // bucket base (uniform across lanes)
  if (lane == 0) bbase[b] = carry;
#pragma unroll
  for (int r = 0; r < 7; ++r) {     // 7*64 = 448 >= 391
    int idx = r * 64 + lane;
    int v = (idx < NCB) ? ghist[(size_t)b * NCB + idx] : 0;
    int s = v;
#pragma unroll
    for (int o = 1; o < 64; o <<= 1) { int t = __shfl_up(s, o, 64); if (lane >= o) s += t; }
    if (idx < NCB) ghist[(size_t)b * NCB + idx] = carry + s - v;
    carry += __shfl(s, 63, 64);
  }
}

// ---------------- merged: GEMM1 (blocks 0..1563) | edge placement (blocks 1564..1954) ----------------
__global__ __launch_bounds__(256) void k_pg1(const float* __restrict__ A, const ushort* __restrict__ Bt,
                                             const float* __restrict__ bp, unsigned char* __restrict__ C,
                                             const int* __restrict__ row, const int* __restrict__ col,
                                             const float* __restrict__ w, const int* __restrict__ ghist,
                                             int2* __restrict__ bdata) {
  __shared__ char smem[32768];
  int bid = blockIdx.x;
  const int tid = threadIdx.x;
  if (bid >= 1564) {
    // ---- edge placement ----
    int* offs = (int*)smem;
    int blk = bid - 1564;
    for (int i = tid; i < NBUCK; i += 256) offs[i] = ghist[(size_t)i * NCB + blk];
    __syncthreads();
    int lo = blk * EPB, hi = lo + EPB; if (hi > NE) hi = NE;
    for (int i = lo + tid * 4; i < hi; i += 1024) {
      int4 r = *(const int4*)(row + i);
      int4 c = *(const int4*)(col + i);
      float4 ww = *(const float4*)(w + i);
      int p;
      p = atomicAdd(&offs[r.x >> 7], 1); bdata[p] = make_int2(((r.x & 127) << 17) | c.x, __float_as_int(ww.x));
      p = atomicAdd(&offs[r.y >> 7], 1); bdata[p] = make_int2(((r.y & 127) << 17) | c.y, __float_as_int(ww.y));
      p = atomicAdd(&offs[r.z >> 7], 1); bdata[p] = make_int2(((r.z & 127) << 17) | c.z, __float_as_int(ww.z));
      p = atomicAdd(&offs[r.w >> 7], 1); bdata[p] = make_int2(((r.w & 127) << 17) | c.w, __float_as_int(ww.w));
    }
    return;
  }
  // ---- GEMM1: C = x[fp32] @ W1t^T + bias, fp8 out ----
  char* sAb = smem;
  char* sBb = smem + 16384;
  const int lane = tid & 63;
  const int wave = tid >> 6;
  const int wm = wave >> 1, wn = wave & 1;
  const int bm = bid >> 1, bn = bid & 1;

  f32x4 acc[4][4];
#pragma unroll
  for (int a = 0; a < 4; ++a)
#pragma unroll
    for (int b = 0; b < 4; ++b) acc[a][b] = (f32x4){0.f, 0.f, 0.f, 0.f};

  const char* Bb = (const char*)Bt;
  for (int kt = 0; kt < 4; ++kt) {
#pragma unroll
    for (int it = 0; it < 4; ++it) {
      int idx = it * 2048 + tid * 8;
      int r = idx >> 6, colx = idx & 63;
      int ra = bm * 128 + r; if (ra >= NN) ra = NN - 1;
      const float* src = A + (size_t)ra * 256 + kt * 64 + colx;
      float4 u = *(const float4*)src;
      float4 v = *(const float4*)(src + 4);
      ushort4 r0; r0.x = f2bf(u.x); r0.y = f2bf(u.y); r0.z = f2bf(u.z); r0.w = f2bf(u.w);
      ushort4 r1; r1.x = f2bf(v.x); r1.y = f2bf(v.y); r1.z = f2bf(v.z); r1.w = f2bf(v.w);
      *(ushort4*)(sAb + r * 128 + colx * 2) = r0;
      *(ushort4*)(sAb + r * 128 + colx * 2 + 8) = r1;
    }
#pragma unroll
    for (int it = 0; it < 4; ++it) {
      int o = tid * 16 + it * 4096;
      int r = o >> 7, kb = o & 127;
      gl2lds16(Bb + (size_t)(bn * 128 + r) * 512 + kt * 128 + kb, sBb + o);
    }
    __syncthreads();
#pragma unroll
    for (int kk = 0; kk < 2; ++kk) {
      int kByte = kk * 64 + ((lane >> 4) << 4);
      bf16x8 af[4], bfr[4];
#pragma unroll
      for (int mi = 0; mi < 4; ++mi)
        af[mi] = *(const bf16x8*)(sAb + (wm * 64 + mi * 16 + (lane & 15)) * 128 + kByte);
#pragma unroll
      for (int ni = 0; ni < 4; ++ni)
        bfr[ni] = *(const bf16x8*)(sBb + (wn * 64 + ni * 16 + (lane & 15)) * 128 + kByte);
#pragma unroll
      for (int mi = 0; mi < 4; ++mi)
#pragma unroll
        for (int ni = 0; ni < 4; ++ni)
          acc[mi][ni] = __builtin_amdgcn_mfma_f32_16x16x32_bf16(af[mi], bfr[ni], acc[mi][ni], 0, 0, 0);
    }
    __syncthreads();
  }

  const int r0 = bm * 128 + wm * 64 + ((lane >> 4) << 2);
  const int c0 = bn * 128 + wn * 64 + (lane & 15);
#pragma unroll
  for (int ni = 0; ni < 4; ++ni) {
    int col2 = c0 + ni * 16;
    float bpv = bp[col2];
#pragma unroll
    for (int mi = 0; mi < 4; ++mi)
#pragma unroll
      for (int i = 0; i < 4; ++i) {
        int r = r0 + mi * 16 + i;
        if (r < NN) C[(size_t)r * 256 + col2] = f2fp8(acc[mi][ni][i] + bpv);
      }
  }
}

// ---------------- per-bucket row sort -> rp + packed cw ----------------
__global__ __launch_bounds__(256) void k_bsort(const int* __restrict__ bcnt, const int* __restrict__ bbase,
                                               const int2* __restrict__ bdata, unsigned* __restrict__ cw,
                                               int* __restrict__ rp) {
  __shared__ int sc[128], lpos[128];
  int b = blockIdx.x, t = threadIdx.x;
  int n = bcnt[b], base = bbase[b];
  if (t < 128) sc[t] = 0;
  __syncthreads();
  for (int i = t; i < n; i += 256) {
    int r = bdata[(size_t)base + i].x >> 17;
    atomicAdd(&sc[r], 1);
  }
  __syncthreads();
  for (int o = 1; o < 128; o <<= 1) {
    int v = (t < 128 && t >= o) ? sc[t - o] : 0;
    __syncthreads();
    if (t < 128) sc[t] += v;
    __syncthreads();
  }
  if (t < 128) {
    int excl = t ? sc[t - 1] : 0;
    lpos[t] = excl;
    int grow = b * 128 + t;
    if (grow <= NN) rp[grow] = base + excl;
  }
  __syncthreads();
  for (int i = t; i < n; i += 256) {
    int2 e = bdata[(size_t)base + i];
    int r = e.x >> 17;
    int p = atomicAdd(&lpos[r], 1);
    cw[base + p] = ((unsigned)(e.x & 0x1FFFF) << 15) | (f2bf(__int_as_float(e.y)) & 0x7FFFu);
  }
}

// ---------------- bf16 MFMA GEMM: C[M x ncst] = A[M x 256] @ Wt^T + bias, fp8 out ----------------
__global__ __launch_bounds__(256) void k_gemm(const ushort* __restrict__ A, const ushort* __restrict__ Bt,
                                              const float* __restrict__ bp, unsigned char* __restrict__ C,
                                              int M, int ldc, int ncst) {
  __shared__ ushort sA[128 * 64];
  __shared__ ushort sB[128 * 64];
  const int tid = threadIdx.x;
  const int lane = tid & 63;
  const int wave = tid >> 6;
  const int wm = wave >> 1, wn = wave & 1;
  const int bm = blockIdx.x, bn = blockIdx.y;

  f32x4 acc[4][4];
#pragma unroll
  for (int a = 0; a < 4; ++a)
#pragma unroll
    for (int b = 0; b < 4; ++b) acc[a][b] = (f32x4){0.f, 0.f, 0.f, 0.f};

  const char* Ab = (const char*)A;
  const char* Bb = (const char*)Bt;
  char* sAb = (char*)sA;
  char* sBb = (char*)sB;

  for (int kt = 0; kt < 4; ++kt) {
#pragma unroll
    for (int it = 0; it < 4; ++it) {
      int o = tid * 16 + it * 4096;
      int r = o >> 7, kb = o & 127;
      int ra = bm * 128 + r; if (ra >= M) ra = M - 1;
      gl2lds16(Ab + (size_t)ra * 512 + kt * 128 + kb, sAb + o);
      gl2lds16(Bb + (size_t)(bn * 128 + r) * 512 + kt * 128 + kb, sBb + o);
    }
    __syncthreads();
#pragma unroll
    for (int kk = 0; kk < 2; ++kk) {
      int kByte = kk * 64 + ((lane >> 4) << 4);
      bf16x8 af[4], bfr[4];
#pragma unroll
      for (int mi = 0; mi < 4; ++mi)
        af[mi] = *(const bf16x8*)(sAb + (wm * 64 + mi * 16 + (lane & 15)) * 128 + kByte);
#pragma unroll
      for (int ni = 0; ni < 4; ++ni)
        bfr[ni] = *(const bf16x8*)(sBb + (wn * 64 + ni * 16 + (lane & 15)) * 128 + kByte);
#pragma unroll
      for (int mi = 0; mi < 4; ++mi)
#pragma unroll
        for (int ni = 0; ni < 4; ++ni)
          acc[mi][ni] = __builtin_amdgcn_mfma_f32_16x16x32_bf16(af[mi], bfr[ni], acc[mi][ni], 0, 0, 0);
    }
    __syncthreads();
  }

  const int r0 = bm * 128 + wm * 64 + ((lane >> 4) << 2);
  const int c0 = bn * 128 + wn * 64 + (lane & 15);
#pragma unroll
  for (int ni = 0; ni < 4; ++ni) {
    int col = c0 + ni * 16;
    if (col >= ncst) continue;
    float bpv = bp[col];
#pragma unroll
    for (int mi = 0; mi < 4; ++mi)
#pragma unroll
      for (int i = 0; i < 4; ++i) {
        int row = r0 + mi * 16 + i;
        if (row < M) C[(size_t)row * ldc + col] = f2fp8(acc[mi][ni][i] + bpv);
      }
  }
}

// gather-accumulate one batch of up to 16 edges (fp8 source, packed 4B cw)
__device__ __forceinline__ void gacc16(const unsigned* __restrict__ cw, int i, int rem,
                                       const char* __restrict__ Hb, f32x2& a01, f32x2& a23) {
  unsigned p[16]; unsigned g[16];
#pragma unroll
  for (int u = 0; u < 16; ++u) p[u] = cw[i + (u < rem ? u : 0)];
#pragma unroll
  for (int u = 0; u < 16; ++u) g[u] = *(const unsigned*)(Hb + ((size_t)(p[u] >> 15) << 8));
#pragma unroll
  for (int u = 0; u < 16; ++u) {
    float wf = (u < rem) ? pw2w(p[u]) : 0.f;
    f32x2 wv = {wf, wf};
    a01 += wv * __builtin_amdgcn_cvt_pk_f32_fp8(g[u], false);
    a23 += wv * __builtin_amdgcn_cvt_pk_f32_fp8(g[u], true);
  }
}

// ---------------- SpMM 256-dim: Y[i,:] = relu(sum w_e * H[col_e,:]), fp8 in, bf16 out ----------------
__global__ __launch_bounds__(256) void k_spmm256(const int* __restrict__ rp, const unsigned* __restrict__ cw,
                                                 const unsigned char* __restrict__ H, ushort* __restrict__ Y) {
  int node = blockIdx.x * 4 + (threadIdx.x >> 6);
  int lane = threadIdx.x & 63;
  int s = __builtin_amdgcn_readfirstlane(rp[node]);
  int e = __builtin_amdgcn_readfirstlane(rp[node + 1]);
  f32x2 a01 = {0.f, 0.f}, a23 = {0.f, 0.f};
  const char* Hb = (const char*)H + (lane << 2);   // 4 fp8 dims per lane
  int i = s;
  for (; i + 16 <= e; i += 16) gacc16(cw, i, 16, Hb, a01, a23);
  int rem = e - i;
  if (rem) gacc16(cw, i, rem, Hb, a01, a23);
  ushort4 o;
  o.x = f2bf(fmaxf(a01.x, 0.f)); o.y = f2bf(fmaxf(a01.y, 0.f));
  o.z = f2bf(fmaxf(a23.x, 0.f)); o.w = f2bf(fmaxf(a23.y, 0.f));
  *(ushort4*)(Y + (size_t)node * 256 + (lane << 2)) = o;
}

// ---------------- SpMM 64-dim + fused log_softmax, fp8 in, fp32 out ----------------
__device__ __forceinline__ void gacc64(const unsigned* __restrict__ cw, int i, int rem,
                                       const unsigned char* __restrict__ H, int word, int shift, float& a) {
  unsigned p[16]; unsigned g[16];
#pragma unroll
  for (int u = 0; u < 16; ++u) p[u] = cw[i + (u < rem ? u : 0)];
#pragma unroll
  for (int u = 0; u < 16; ++u)
    g[u] = *(const unsigned*)(H + ((size_t)(p[u] >> 15) << 6) + word);
#pragma unroll
  for (int u = 0; u < 16; ++u) {
    float h = __builtin_amdgcn_cvt_f32_fp8(g[u] >> shift, 0);
    a += ((u < rem) ? pw2w(p[u]) : 0.f) * h;
  }
}

__global__ __launch_bounds__(256) void k_spmm64(const int* __restrict__ rp, const unsigned* __restrict__ cw,
                                                const unsigned char* __restrict__ H, float* __restrict__ out) {
  int node = blockIdx.x * 4 + (threadIdx.x >> 6);
  int lane = threadIdx.x & 63;
  int s = __builtin_amdgcn_readfirstlane(rp[node]);
  int e = __builtin_amdgcn_readfirstlane(rp[node + 1]);
  int word = (lane >> 2) << 2;      // dword offset within 64B row
  int shift = (lane & 3) << 3;      // byte within dword
  float a = 0.f;
  int i = s;
  for (; i + 16 <= e; i += 16) gacc64(cw, i, 16, H, word, shift, a);
  int rem = e - i;
  if (rem) gacc64(cw, i, rem, H, word, shift, a);
  float mx = a;
#pragma unroll
  for (int o = 32; o > 0; o >>= 1) mx = fmaxf(mx, __shfl_xor(mx, o, 64));
  float ex = expf(a - mx);
  float sum = ex;
#pragma unroll
  for (int o = 32; o > 0; o >>= 1) sum += __shfl_xor(sum, o, 64);
  out[(size_t)node * 64 + lane] = (a - mx) - logf(sum);
}

extern "C" void kernel_launch(void* const* d_in, const int* in_sizes, int n_in,
                              void* d_out, int out_size, void* d_ws, size_t ws_size,
                              hipStream_t stream) {
  const float* x   = (const float*)d_in[0];
  const int* erow  = (const int*)d_in[1];
  const int* ecol  = (const int*)d_in[2];
  const float* ew  = (const float*)d_in[3];
  const float* W1  = (const float*)d_in[4];
  const float* b1  = (const float*)d_in[5];
  const float* g1  = (const float*)d_in[6];
  const float* be1 = (const float*)d_in[7];
  const float* m1  = (const float*)d_in[8];
  const float* v1  = (const float*)d_in[9];
  const float* W2  = (const float*)d_in[10];
  const float* b2  = (const float*)d_in[11];
  const float* g2  = (const float*)d_in[12];
  const float* be2 = (const float*)d_in[13];
  const float* m2  = (const float*)d_in[14];
  const float* v2  = (const float*)d_in[15];
  const float* W3  = (const float*)d_in[16];
  const float* b3  = (const float*)d_in[17];

  char* ws = (char*)d_ws;
  size_t off = 0;
  auto carve = [&](size_t bytes) -> void* {
    void* p = ws + off;
    off += (bytes + 511) & ~(size_t)511;
    return p;
  };
  int* bcnt    = (int*)carve((size_t)NBUCK * 4);
  int* bbase   = (int*)carve((size_t)NBUCK * 4);
  int* ghist   = (int*)carve((size_t)NBUCK * NCB * 4);
  int* rp      = (int*)carve((size_t)(NBUCK * 128 + 1) * 4);
  unsigned* cw = (unsigned*)carve((size_t)NE * 4);
  ushort* W1t  = (ushort*)carve(256 * 256 * 2);
  ushort* W2t  = (ushort*)carve(256 * 256 * 2);
  ushort* W3t  = (ushort*)carve(128 * 256 * 2);
  float* bp1   = (float*)carve(256 * 4);
  float* bp2   = (float*)carve(256 * 4);
  float* bp3   = (float*)carve(128 * 4);
  ushort* bufH        = (ushort*)carve((size_t)NN * 256 * 2);        // bf16: h1, h2 (+ CSR scratch)
  unsigned char* bufZ = (unsigned char*)carve((size_t)NN * 256);     // fp8: z1, z2
  unsigned char* bufZ3 = (unsigned char*)carve((size_t)NN * 64);     // fp8: z3
  if (off > ws_size) return;

  // bucket scratch aliases bufH (not live until spmm1 writes h1): NE*8 = 25.6MB <= 51.2MB
  int2* bdata = (int2*)bufH;

  hipMemsetAsync(bcnt, 0, (size_t)NBUCK * 4, stream);
  // weight prep | edge histogram
  k_pc<<<1031, 256, 0, stream>>>(W1, b1, g1, be1, m1, v1, W2, b2, g2, be2, m2, v2, W3, b3,
                                 W1t, W2t, W3t, bp1, bp2, bp3, erow, ghist, bcnt);
  // per-bucket offset scan (self-computed bases)
  k_scan3<<<NBUCK, 64, 0, stream>>>(ghist, bcnt, bbase);
  // GEMM1 (z1 = x @ W1' + b1', fp8 out) | edge placement
  k_pg1<<<1955, 256, 0, stream>>>(x, W1t, bp1, bufZ, erow, ecol, ew, ghist, bdata);
  // row sort -> rp + packed cw
  k_bsort<<<NBUCK, 256, 0, stream>>>(bcnt, bbase, bdata, cw, rp);

  const int gm = (NN + 127) / 128;
  // h1 = relu(P @ z1)
  k_spmm256<<<NN / 4, 256, 0, stream>>>(rp, cw, bufZ, bufH);
  // layer 2: z2 = h1 @ W2' + b2'
  k_gemm<<<dim3(gm, 2), 256, 0, stream>>>(bufH, W2t, bp2, bufZ, NN, 256, 256);
  // h2 = relu(P @ z2)
  k_spmm256<<<NN / 4, 256, 0, stream>>>(rp, cw, bufZ, bufH);
  // layer 3: z3 = h2 @ W3 + b3
  k_gemm<<<dim3(gm, 1), 256, 0, stream>>>(bufH, W3t, bp3, bufZ3, NN, 64, 64);
  // out = log_softmax(P @ z3)
  k_spmm64<<<NN / 4, 256, 0, stream>>>(rp, cw, bufZ3, (float*)d_out);
}